// Round 9
// baseline (242.446 us; speedup 1.0000x reference)
//
#include <hip/hip_runtime.h>

typedef __bf16 bf16_t;
typedef __bf16 bf16x8 __attribute__((ext_vector_type(8)));
typedef __bf16 bf16x4 __attribute__((ext_vector_type(4)));
typedef float f32x4 __attribute__((ext_vector_type(4)));

#define B_  2
#define N_  2048
#define D_  1024
#define H_  16
#define DH_ 64

// Q pre-scale: (1/sqrt(64)) * log2(e) so softmax can use raw v_exp_f32 (2^x)
#define QSCALE 0.18033688011112042f
// 8 * log2(e): folded into QK^T accumulator init => st = log2e*(s - 8)
#define NEGC  -11.541560327111707f

#if __has_builtin(__builtin_amdgcn_exp2f)
#define EXP2F(x) __builtin_amdgcn_exp2f(x)
#else
#define EXP2F(x) exp2f(x)
#endif

#define GLL16(g, l) __builtin_amdgcn_global_load_lds( \
    (const __attribute__((address_space(1))) void*)(g), \
    (__attribute__((address_space(3))) void*)(l), 16, 0, 0)

// XCD-aware chunked swizzle (T1). Requires nwg % 8 == 0 (all our grids comply).
__device__ __forceinline__ int xcd_swizzle_id() {
  int id = blockIdx.y * gridDim.x + blockIdx.x;
  int cpx = (gridDim.x * gridDim.y) >> 3;
  return (id & 7) * cpx + (id >> 3);
}

// ---------------- trig table: tc/ts[n][j] = cos/sin(n * freqs[j]), n<2048, j<32 ----------------
__global__ __launch_bounds__(256) void k_trig(const float* __restrict__ freqs,
    float* __restrict__ tc, float* __restrict__ ts) {
  int idx = blockIdx.x * 256 + threadIdx.x;   // 65536 total
  int n = idx >> 5, j = idx & 31;
  float f = (float)n * freqs[j];
  tc[idx] = cosf(f);
  ts[idx] = sinf(f);
}

// ---------------- RMSNorm + fused gates ----------------
__global__ __launch_bounds__(256) void k_rmsnorm_gates(const float* __restrict__ x,
    const float* __restrict__ gamma, const float* __restrict__ wg,
    const float* __restrict__ bg, bf16_t* __restrict__ xn, float* __restrict__ gsig) {
  int row = blockIdx.x;
  const float4* xr = (const float4*)(x + (size_t)row * D_);
  int tid = threadIdx.x;
  float4 v = xr[tid];
  float ss = v.x*v.x + v.y*v.y + v.z*v.z + v.w*v.w;
  #pragma unroll
  for (int off = 32; off > 0; off >>= 1) ss += __shfl_down(ss, off);
  __shared__ float red4[4];
  if ((tid & 63) == 0) red4[tid >> 6] = ss;
  __syncthreads();
  float scale = 32.0f * rsqrtf(red4[0] + red4[1] + red4[2] + red4[3]);
  float4 g = ((const float4*)gamma)[tid];
  bf16x4 o;
  o[0] = (bf16_t)(v.x * scale * g.x);
  o[1] = (bf16_t)(v.y * scale * g.y);
  o[2] = (bf16_t)(v.z * scale * g.z);
  o[3] = (bf16_t)(v.w * scale * g.w);
  *(bf16x4*)(xn + (size_t)row * D_ + tid * 4) = o;
  // ---- fused gates ----
  float xv[4] = {(float)o[0], (float)o[1], (float)o[2], (float)o[3]};
  float part[16];
  #pragma unroll
  for (int h = 0; h < 16; ++h) part[h] = 0.f;
  #pragma unroll
  for (int j = 0; j < 4; ++j) {
    const float4* wr = (const float4*)&wg[(size_t)(tid * 4 + j) * 16];
    #pragma unroll
    for (int q = 0; q < 4; ++q) {
      float4 w4 = wr[q];
      part[q * 4 + 0] += xv[j] * w4.x;
      part[q * 4 + 1] += xv[j] * w4.y;
      part[q * 4 + 2] += xv[j] * w4.z;
      part[q * 4 + 3] += xv[j] * w4.w;
    }
  }
  __shared__ float red[256][17];   // stride-17: 2-way bank aliasing only (free)
  #pragma unroll
  for (int h = 0; h < 16; ++h) red[tid][h] = part[h];
  __syncthreads();
  int h = tid & 15, grp = tid >> 4;
  float s = 0.f;
  #pragma unroll
  for (int k = 0; k < 16; ++k) s += red[grp * 16 + k][h];
  __syncthreads();
  red[grp][h] = s;
  __syncthreads();
  if (tid < 16) {
    float acc = bg[tid];
    #pragma unroll
    for (int k = 0; k < 16; ++k) acc += red[k][tid];
    gsig[(size_t)row * 16 + tid] = 1.0f / (1.0f + __expf(-acc));
  }
}

// ---------------- transpose fp32 [R][C] -> bf16 [C][R] ----------------
__global__ __launch_bounds__(256) void k_transpose_cvt(const float* __restrict__ W,
    bf16_t* __restrict__ Wt, int R, int C) {
  __shared__ float tile[32][33];
  int c0 = blockIdx.x * 32, r0 = blockIdx.y * 32;
  int tx = threadIdx.x & 31, ty = threadIdx.x >> 5;
  #pragma unroll
  for (int i = 0; i < 4; ++i) {
    int r = ty + i * 8;
    tile[r][tx] = W[(size_t)(r0 + r) * C + c0 + tx];
  }
  __syncthreads();
  #pragma unroll
  for (int i = 0; i < 4; ++i) {
    int rr = ty + i * 8;
    Wt[(size_t)(c0 + rr) * R + r0 + tx] = (bf16_t)tile[tx][rr];
  }
}

// ---------------- QKV GEMM with fused RoPE + scatter epilogue ----------------
// C[4096][3072] = xn[4096][1024] * wqkvT[3072][1024]^T.
// Column-block regions: byi 0-7 -> Q (RoPE + QSCALE), 8-15 -> K (RoPE),
// 16-23 -> V (transposed [bh][d][n] store, bf16x4 along n).
// RoPE on unrounded fp32 acc; pairs (2j,2j+1) are adjacent lanes -> shfl_xor(1).
__global__ __launch_bounds__(256) void k_gemm_qkv(const bf16_t* __restrict__ A,
    const bf16_t* __restrict__ Bt, const float* __restrict__ tc,
    const float* __restrict__ ts, bf16_t* __restrict__ Qb,
    bf16_t* __restrict__ Kb, bf16_t* __restrict__ Vb) {
  constexpr int BK = 32, K = 1024;
  __shared__ __align__(16) bf16_t As[128 * BK];
  __shared__ __align__(16) bf16_t Bs[128 * BK];
  int tid = threadIdx.x, wave = tid >> 6, lane = tid & 63;
  int l16 = lane & 15, quad = lane >> 4;
  int swz = xcd_swizzle_id();                 // grid (32,24): nwg=768, %8==0
  int bxi = swz % 32, byi = swz / 32;
  int bm = bxi * 128, bn = byi * 128;
  int wm = (wave >> 1) * 64, wn = (wave & 1) * 64;
  int srow = wave * 32 + (lane >> 2);
  int scol = (lane & 3) * 8;
  const bf16_t* gA0 = &A [(size_t)(bm + srow)      * K + scol];
  const bf16_t* gA1 = &A [(size_t)(bm + srow + 16) * K + scol];
  const bf16_t* gB0 = &Bt[(size_t)(bn + srow)      * K + scol];
  const bf16_t* gB1 = &Bt[(size_t)(bn + srow + 16) * K + scol];
  bf16_t* lA0 = &As[(wave * 32)      * BK];
  bf16_t* lA1 = &As[(wave * 32 + 16) * BK];
  bf16_t* lB0 = &Bs[(wave * 32)      * BK];
  bf16_t* lB1 = &Bs[(wave * 32 + 16) * BK];
  f32x4 acc[4][4] = {};
  for (int k0 = 0; k0 < K; k0 += BK) {
    GLL16(gA0 + k0, lA0);
    GLL16(gA1 + k0, lA1);
    GLL16(gB0 + k0, lB0);
    GLL16(gB1 + k0, lB1);
    __syncthreads();
    bf16x8 af[4], bfr[4];
    #pragma unroll
    for (int t = 0; t < 4; ++t) {
      af[t]  = *(const bf16x8*)&As[(wm + t * 16 + l16) * BK + quad * 8];
      bfr[t] = *(const bf16x8*)&Bs[(wn + t * 16 + l16) * BK + quad * 8];
    }
    #pragma unroll
    for (int mt = 0; mt < 4; ++mt)
      #pragma unroll
      for (int nt = 0; nt < 4; ++nt)
        acc[mt][nt] = __builtin_amdgcn_mfma_f32_16x16x32_bf16(af[mt], bfr[nt], acc[mt][nt], 0, 0, 0);
    __syncthreads();
  }
  // ---- fused epilogue ----
  if (byi < 16) {
    // Q or K: RoPE. col in [0,2048); h = (col>>6)&15, d = col&63, j = d>>1.
    float qs = (byi < 8) ? QSCALE : 1.0f;
    bf16_t* dst = (byi < 8) ? Qb : Kb;
    #pragma unroll
    for (int mt = 0; mt < 4; ++mt)
      #pragma unroll
      for (int r = 0; r < 4; ++r) {
        int row = bm + wm + mt * 16 + quad * 4 + r;
        int b = row >> 11, n = row & 2047;
        const float* cr = tc + n * 32;
        const float* sr = ts + n * 32;
        #pragma unroll
        for (int nt = 0; nt < 4; ++nt) {
          int col = bn + wn + nt * 16 + l16;
          int h = (col >> 6) & 15, d = col & 63, j = d >> 1;
          float val = acc[mt][nt][r];
          float p = __shfl_xor(val, 1);         // partner element of the pair
          float c = cr[j], s = sr[j];
          float o = (d & 1) ? (val * c + p * s) : (val * c - p * s);
          dst[((size_t)(b * H_ + h) * N_ + n) * DH_ + d] = (bf16_t)(o * qs);
        }
      }
  } else {
    // V: transposed store Vb[bh][d][n]; 4 consecutive n per fragment -> bf16x4.
    #pragma unroll
    for (int mt = 0; mt < 4; ++mt)
      #pragma unroll
      for (int nt = 0; nt < 4; ++nt) {
        int row0 = bm + wm + mt * 16 + quad * 4;
        int b = row0 >> 11, n0 = row0 & 2047;
        int col = bn + wn + nt * 16 + l16;      // 2048..3071
        int h = (col >> 6) & 15, d = col & 63;
        bf16x4 pk;
        #pragma unroll
        for (int r = 0; r < 4; ++r) pk[r] = (bf16_t)acc[mt][nt][r];
        *(bf16x4*)&Vb[((size_t)(b * H_ + h) * DH_ + d) * N_ + n0] = pk;
      }
  }
}

// ---------------- GEMM: 128x64 tile (fp32 out) — for N=1024 out-proj ----------------
__global__ __launch_bounds__(256) void k_gemm_bt_n64(const bf16_t* __restrict__ A,
    const bf16_t* __restrict__ Bt, float* __restrict__ C, int M, int N, int K) {
  constexpr int BK = 32;
  __shared__ __align__(16) bf16_t As[128 * BK];
  __shared__ __align__(16) bf16_t Bs[64 * BK];
  int tid = threadIdx.x, wave = tid >> 6, lane = tid & 63;
  int l16 = lane & 15, quad = lane >> 4;
  int swz = xcd_swizzle_id();
  int bxi = swz % gridDim.x, byi = swz / gridDim.x;
  int bm = bxi * 128, bn = byi * 64;
  int wm = (wave >> 1) * 64, wn = (wave & 1) * 32;
  int srow = wave * 32 + (lane >> 2);
  int scol = (lane & 3) * 8;
  const bf16_t* gA0 = &A [(size_t)(bm + srow)      * K + scol];
  const bf16_t* gA1 = &A [(size_t)(bm + srow + 16) * K + scol];
  int srB = wave * 16 + (lane >> 2);
  const bf16_t* gB0 = &Bt[(size_t)(bn + srB) * K + scol];
  bf16_t* lA0 = &As[(wave * 32)      * BK];
  bf16_t* lA1 = &As[(wave * 32 + 16) * BK];
  bf16_t* lB0 = &Bs[(wave * 16)      * BK];
  f32x4 acc[4][2] = {};
  for (int k0 = 0; k0 < K; k0 += BK) {
    GLL16(gA0 + k0, lA0);
    GLL16(gA1 + k0, lA1);
    GLL16(gB0 + k0, lB0);
    __syncthreads();
    bf16x8 af[4], bfr[2];
    #pragma unroll
    for (int t = 0; t < 4; ++t)
      af[t]  = *(const bf16x8*)&As[(wm + t * 16 + l16) * BK + quad * 8];
    #pragma unroll
    for (int t = 0; t < 2; ++t)
      bfr[t] = *(const bf16x8*)&Bs[(wn + t * 16 + l16) * BK + quad * 8];
    #pragma unroll
    for (int mt = 0; mt < 4; ++mt)
      #pragma unroll
      for (int nt = 0; nt < 2; ++nt)
        acc[mt][nt] = __builtin_amdgcn_mfma_f32_16x16x32_bf16(af[mt], bfr[nt], acc[mt][nt], 0, 0, 0);
    __syncthreads();
  }
  #pragma unroll
  for (int mt = 0; mt < 4; ++mt)
    #pragma unroll
    for (int nt = 0; nt < 2; ++nt)
      #pragma unroll
      for (int r = 0; r < 4; ++r) {
        int row = bm + wm + mt * 16 + quad * 4 + r;
        int col = bn + wn + nt * 16 + l16;
        C[(size_t)row * N + col] = acc[mt][nt][r];
      }
}

// ---------------- flash attention: S^T form, fixed-max softmax, 32 q/wave ----------------
// v5 (measured 53.4 µs, MfmaUtil 28%, FETCH 12.8MB): XCD swizzle; softmax 2^x
// (log2e folded into Q-scale, -8*log2e into C-init); row-sum via ones-MFMA;
// dbuf K/V + async-STAGE + setprio; single barrier/tile.
__global__ __launch_bounds__(256) void k_flash(const bf16_t* __restrict__ Qb,
    const bf16_t* __restrict__ Kb, const bf16_t* __restrict__ Vb,
    const float* __restrict__ gsig, bf16_t* __restrict__ Ao) {
  __shared__ __align__(16) bf16_t Ks[2][64 * 72];    // [buf][key][dh], stride 72
  __shared__ __align__(16) bf16_t Vt[2][64 * 72];    // [buf][dh][key], stride 72
  __shared__ __align__(16) bf16_t Ps[4][32 * 72];    // per-wave [q][key], stride 72
  int swz = xcd_swizzle_id();                        // grid (16, 32): nwg=512, %8==0
  int qblk = swz & 15, bh = swz >> 4;
  int b = bh >> 4, h = bh & 15;
  int tid = threadIdx.x, wave = tid >> 6, lane = tid & 63;
  int l16 = lane & 15, quad = lane >> 4;
  int qw = qblk * 128 + wave * 32;
  const bf16_t* Qh = Qb + (size_t)bh * N_ * DH_;
  const bf16_t* Kh = Kb + (size_t)bh * N_ * DH_;
  const bf16_t* Vh = Vb + (size_t)bh * DH_ * N_;     // [64][2048]
  bf16_t* Pw = Ps[wave];
  bf16x8 qf[2][2];
  #pragma unroll
  for (int qt = 0; qt < 2; ++qt)
    #pragma unroll
    for (int hf = 0; hf < 2; ++hf)
      qf[qt][hf] = *(const bf16x8*)&Qh[(size_t)(qw + qt * 16 + l16) * DH_ + hf * 32 + quad * 8];
  bf16x8 onesf;
  #pragma unroll
  for (int i = 0; i < 8; ++i) onesf[i] = (bf16_t)1.0f;
  f32x4 accO[2][4] = {};
  f32x4 accL[2] = {};                // row-sum via ones-MFMA; same layout as accO
  int sk = tid >> 3;                 // 0..31
  int sc = (tid & 7) * 8;
  // ---- prologue: stage tile 0 into buf 0 ----
  bf16x8 rk0 = *(const bf16x8*)&Kh[(size_t)sk * DH_ + sc];
  bf16x8 rk1 = *(const bf16x8*)&Kh[(size_t)(sk + 32) * DH_ + sc];
  bf16x8 rv0 = *(const bf16x8*)&Vh[(size_t)sk * N_ + sc];
  bf16x8 rv1 = *(const bf16x8*)&Vh[(size_t)(sk + 32) * N_ + sc];
  *(bf16x8*)&Ks[0][sk * 72 + sc]        = rk0;
  *(bf16x8*)&Ks[0][(sk + 32) * 72 + sc] = rk1;
  *(bf16x8*)&Vt[0][sk * 72 + sc]        = rv0;
  *(bf16x8*)&Vt[0][(sk + 32) * 72 + sc] = rv1;
  __syncthreads();
  const f32x4 zinit = {NEGC, NEGC, NEGC, NEGC};
  for (int k0 = 0; k0 < N_; k0 += 64) {
    int cur = (k0 >> 6) & 1;
    const bf16_t* Kc = Ks[cur];
    const bf16_t* Vc = Vt[cur];
    int kn = k0 + 64;
    if (kn < N_) {
      rk0 = *(const bf16x8*)&Kh[(size_t)(kn + sk) * DH_ + sc];
      rk1 = *(const bf16x8*)&Kh[(size_t)(kn + sk + 32) * DH_ + sc];
      rv0 = *(const bf16x8*)&Vh[(size_t)sk * N_ + kn + sc];
      rv1 = *(const bf16x8*)&Vh[(size_t)(sk + 32) * N_ + kn + sc];
    }
    // S^T = K . Q^T -> C[key][q]; C-init = -8*log2e so st = log2e*(s-8)
    f32x4 st[4][2];
    __builtin_amdgcn_s_setprio(1);
    #pragma unroll
    for (int kt = 0; kt < 4; ++kt) {
      bf16x8 kf0 = *(const bf16x8*)&Kc[(kt * 16 + l16) * 72 + quad * 8];
      bf16x8 kf1 = *(const bf16x8*)&Kc[(kt * 16 + l16) * 72 + 32 + quad * 8];
      #pragma unroll
      for (int qt = 0; qt < 2; ++qt) {
        f32x4 z = zinit;
        z = __builtin_amdgcn_mfma_f32_16x16x32_bf16(kf0, qf[qt][0], z, 0, 0, 0);
        z = __builtin_amdgcn_mfma_f32_16x16x32_bf16(kf1, qf[qt][1], z, 0, 0, 0);
        st[kt][qt] = z;
      }
    }
    __builtin_amdgcn_s_setprio(0);
    // softmax: p = 2^st (bare v_exp_f32)
    #pragma unroll
    for (int qt = 0; qt < 2; ++qt)
      #pragma unroll
      for (int kt = 0; kt < 4; ++kt) {
        bf16x4 pk;
        #pragma unroll
        for (int r = 0; r < 4; ++r)
          pk[r] = (bf16_t)EXP2F(st[kt][qt][r]);
        *(bf16x4*)&Pw[(qt * 16 + l16) * 72 + kt * 16 + quad * 4] = pk;
      }
    // P fragments (A-operand) + PV; row-sum via ones-MFMA on the matrix pipe
    bf16x8 pf[2][2];
    #pragma unroll
    for (int qt = 0; qt < 2; ++qt)
      #pragma unroll
      for (int hf = 0; hf < 2; ++hf)
        pf[qt][hf] = *(const bf16x8*)&Pw[(qt * 16 + l16) * 72 + hf * 32 + quad * 8];
    __builtin_amdgcn_s_setprio(1);
    #pragma unroll
    for (int qt = 0; qt < 2; ++qt) {
      accL[qt] = __builtin_amdgcn_mfma_f32_16x16x32_bf16(pf[qt][0], onesf, accL[qt], 0, 0, 0);
      accL[qt] = __builtin_amdgcn_mfma_f32_16x16x32_bf16(pf[qt][1], onesf, accL[qt], 0, 0, 0);
    }
    #pragma unroll
    for (int dt = 0; dt < 4; ++dt)
      #pragma unroll
      for (int hf = 0; hf < 2; ++hf) {
        bf16x8 vf = *(const bf16x8*)&Vc[(dt * 16 + l16) * 72 + hf * 32 + quad * 8];
        #pragma unroll
        for (int qt = 0; qt < 2; ++qt)
          accO[qt][dt] = __builtin_amdgcn_mfma_f32_16x16x32_bf16(pf[qt][hf], vf, accO[qt][dt], 0, 0, 0);
      }
    __builtin_amdgcn_s_setprio(0);
    if (kn < N_) {
      int nb = cur ^ 1;
      *(bf16x8*)&Ks[nb][sk * 72 + sc]        = rk0;
      *(bf16x8*)&Ks[nb][(sk + 32) * 72 + sc] = rk1;
      *(bf16x8*)&Vt[nb][sk * 72 + sc]        = rv0;
      *(bf16x8*)&Vt[nb][(sk + 32) * 72 + sc] = rv1;
    }
    __syncthreads();
  }
  // epilogue: O and L are both in C layout (q = qt*16+quad*4+r, d = dt*16+l16)
  #pragma unroll
  for (int qt = 0; qt < 2; ++qt)
    #pragma unroll
    for (int r = 0; r < 4; ++r) {
      int q = qw + qt * 16 + quad * 4 + r;
      float g = gsig[((size_t)b * N_ + q) * H_ + h];
      float ginv = g / accL[qt][r];
      #pragma unroll
      for (int dt = 0; dt < 4; ++dt)
        Ao[((size_t)b * N_ + q) * (H_ * DH_) + h * DH_ + dt * 16 + l16] =
            (bf16_t)(accO[qt][dt][r] * ginv);
    }
}

extern "C" void kernel_launch(void* const* d_in, const int* in_sizes, int n_in,
                              void* d_out, int out_size, void* d_ws, size_t ws_size,
                              hipStream_t stream) {
  (void)in_sizes; (void)n_in; (void)out_size; (void)ws_size;
  const float* x      = (const float*)d_in[0];
  const float* gamma  = (const float*)d_in[1];
  const float* w_qkv  = (const float*)d_in[2];
  const float* w_gate = (const float*)d_in[3];
  const float* b_gate = (const float*)d_in[4];
  const float* w_out  = (const float*)d_in[5];
  const float* freqs  = (const float*)d_in[6];
  float* out = (float*)d_out;
  char* ws = (char*)d_ws;
  bf16_t* xn    = (bf16_t*)(ws);                          // 8 MB
  bf16_t* wqkvT = (bf16_t*)(ws + ((size_t)8  << 20));     // 6 MB
  bf16_t* woutT = (bf16_t*)(ws + ((size_t)14 << 20));     // 2 MB
  bf16_t* Qb    = (bf16_t*)(ws + ((size_t)16 << 20));     // 8 MB [bh][n][64]
  bf16_t* Kb    = (bf16_t*)(ws + ((size_t)24 << 20));     // 8 MB [bh][n][64]
  bf16_t* Vb    = (bf16_t*)(ws + ((size_t)32 << 20));     // 8 MB [bh][64][n]
  float*  gsig  = (float*) (ws + ((size_t)40 << 20));     // 256 KB
  bf16_t* attn  = (bf16_t*)(ws + ((size_t)41 << 20));     // 8 MB
  float*  trigc = (float*) (ws + ((size_t)49 << 20));     // 256 KB
  float*  trigs = (float*) (ws + ((size_t)50 << 20));     // 256 KB

  k_trig<<<256, 256, 0, stream>>>(freqs, trigc, trigs);
  k_transpose_cvt<<<dim3(3072 / 32, 1024 / 32), 256, 0, stream>>>(w_qkv, wqkvT, 1024, 3072);
  k_transpose_cvt<<<dim3(1024 / 32, 1024 / 32), 256, 0, stream>>>(w_out, woutT, 1024, 1024);
  k_rmsnorm_gates<<<4096, 256, 0, stream>>>(x, gamma, w_gate, b_gate, xn, gsig);
  k_gemm_qkv<<<dim3(32, 24), 256, 0, stream>>>(xn, wqkvT, trigc, trigs, Qb, Kb, Vb);
  k_flash<<<dim3(16, 32), 256, 0, stream>>>(Qb, Kb, Vb, gsig, attn);
  k_gemm_bt_n64<<<dim3(32, 16), 256, 0, stream>>>(attn, woutT, out, 4096, 1024, 1024);
}

// Round 10
// 239.711 us; speedup vs baseline: 1.0114x; 1.0114x over previous
//
#include <hip/hip_runtime.h>

typedef __bf16 bf16_t;
typedef __bf16 bf16x8 __attribute__((ext_vector_type(8)));
typedef __bf16 bf16x4 __attribute__((ext_vector_type(4)));
typedef float f32x4 __attribute__((ext_vector_type(4)));

#define B_  2
#define N_  2048
#define D_  1024
#define H_  16
#define DH_ 64

// Q pre-scale: (1/sqrt(64)) * log2(e) so softmax can use raw v_exp_f32 (2^x)
#define QSCALE 0.18033688011112042f
// 8 * log2(e): folded into QK^T accumulator init => st = log2e*(s - 8)
#define NEGC  -11.541560327111707f

#if __has_builtin(__builtin_amdgcn_exp2f)
#define EXP2F(x) __builtin_amdgcn_exp2f(x)
#else
#define EXP2F(x) exp2f(x)
#endif

#define GLL16(g, l) __builtin_amdgcn_global_load_lds( \
    (const __attribute__((address_space(1))) void*)(g), \
    (__attribute__((address_space(3))) void*)(l), 16, 0, 0)

// XCD-aware chunked swizzle (T1). Requires nwg % 8 == 0 (all our grids comply).
__device__ __forceinline__ int xcd_swizzle_id() {
  int id = blockIdx.y * gridDim.x + blockIdx.x;
  int cpx = (gridDim.x * gridDim.y) >> 3;
  return (id & 7) * cpx + (id >> 3);
}

// ---------------- trig table: tc/ts[n][j] = cos/sin(n * freqs[j]), n<2048, j<32 ----------------
__global__ __launch_bounds__(256) void k_trig(const float* __restrict__ freqs,
    float* __restrict__ tc, float* __restrict__ ts) {
  int idx = blockIdx.x * 256 + threadIdx.x;   // 65536 total
  int n = idx >> 5, j = idx & 31;
  float f = (float)n * freqs[j];
  tc[idx] = cosf(f);
  ts[idx] = sinf(f);
}

// ---------------- RMSNorm + fused gates ----------------
__global__ __launch_bounds__(256) void k_rmsnorm_gates(const float* __restrict__ x,
    const float* __restrict__ gamma, const float* __restrict__ wg,
    const float* __restrict__ bg, bf16_t* __restrict__ xn, float* __restrict__ gsig) {
  int row = blockIdx.x;
  const float4* xr = (const float4*)(x + (size_t)row * D_);
  int tid = threadIdx.x;
  float4 v = xr[tid];
  float ss = v.x*v.x + v.y*v.y + v.z*v.z + v.w*v.w;
  #pragma unroll
  for (int off = 32; off > 0; off >>= 1) ss += __shfl_down(ss, off);
  __shared__ float red4[4];
  if ((tid & 63) == 0) red4[tid >> 6] = ss;
  __syncthreads();
  float scale = 32.0f * rsqrtf(red4[0] + red4[1] + red4[2] + red4[3]);
  float4 g = ((const float4*)gamma)[tid];
  bf16x4 o;
  o[0] = (bf16_t)(v.x * scale * g.x);
  o[1] = (bf16_t)(v.y * scale * g.y);
  o[2] = (bf16_t)(v.z * scale * g.z);
  o[3] = (bf16_t)(v.w * scale * g.w);
  *(bf16x4*)(xn + (size_t)row * D_ + tid * 4) = o;
  // ---- fused gates ----
  float xv[4] = {(float)o[0], (float)o[1], (float)o[2], (float)o[3]};
  float part[16];
  #pragma unroll
  for (int h = 0; h < 16; ++h) part[h] = 0.f;
  #pragma unroll
  for (int j = 0; j < 4; ++j) {
    const float4* wr = (const float4*)&wg[(size_t)(tid * 4 + j) * 16];
    #pragma unroll
    for (int q = 0; q < 4; ++q) {
      float4 w4 = wr[q];
      part[q * 4 + 0] += xv[j] * w4.x;
      part[q * 4 + 1] += xv[j] * w4.y;
      part[q * 4 + 2] += xv[j] * w4.z;
      part[q * 4 + 3] += xv[j] * w4.w;
    }
  }
  __shared__ float red[256][17];   // stride-17: 2-way bank aliasing only (free)
  #pragma unroll
  for (int h = 0; h < 16; ++h) red[tid][h] = part[h];
  __syncthreads();
  int h = tid & 15, grp = tid >> 4;
  float s = 0.f;
  #pragma unroll
  for (int k = 0; k < 16; ++k) s += red[grp * 16 + k][h];
  __syncthreads();
  red[grp][h] = s;
  __syncthreads();
  if (tid < 16) {
    float acc = bg[tid];
    #pragma unroll
    for (int k = 0; k < 16; ++k) acc += red[k][tid];
    gsig[(size_t)row * 16 + tid] = 1.0f / (1.0f + __expf(-acc));
  }
}

// ---------------- transpose fp32 [R][C] -> bf16 [C][R] ----------------
__global__ __launch_bounds__(256) void k_transpose_cvt(const float* __restrict__ W,
    bf16_t* __restrict__ Wt, int R, int C) {
  __shared__ float tile[32][33];
  int c0 = blockIdx.x * 32, r0 = blockIdx.y * 32;
  int tx = threadIdx.x & 31, ty = threadIdx.x >> 5;
  #pragma unroll
  for (int i = 0; i < 4; ++i) {
    int r = ty + i * 8;
    tile[r][tx] = W[(size_t)(r0 + r) * C + c0 + tx];
  }
  __syncthreads();
  #pragma unroll
  for (int i = 0; i < 4; ++i) {
    int rr = ty + i * 8;
    Wt[(size_t)(c0 + rr) * R + r0 + tx] = (bf16_t)tile[tx][rr];
  }
}

// ---------------- QKV GEMM with fused RoPE + LDS-staged coalesced epilogue ----------------
// v2 of the fusion (v1 measured 72.7us, MfmaUtil 14%, FETCH 71.5MB):
//  - scatter stores replaced by LDS-staged bf16x8 coalesced flush (v1's +23us regression
//    was 2B/8B scattered stores: 16-64 transactions per store instruction).
//  - 2D XCD chunking: each XCD owns an 8x12 block rectangle -> unique bytes/XCD
//    5MB vs 8.75MB for the 1D chunk (FETCH was 8 XCDs x all-of-A).
// Column regions: byi 0-7 -> Q (RoPE+QSCALE), 8-15 -> K (RoPE), 16-23 -> V (store [bh][d][n]).
__global__ __launch_bounds__(256) void k_gemm_qkv(const bf16_t* __restrict__ A,
    const bf16_t* __restrict__ Bt, const float* __restrict__ tc,
    const float* __restrict__ ts, bf16_t* __restrict__ Qb,
    bf16_t* __restrict__ Kb, bf16_t* __restrict__ Vb) {
  constexpr int BK = 32, K = 1024;
  constexpr int TP = 136;                    // LDS tile stride (pad 8 bf16)
  __shared__ __align__(16) bf16_t As[128 * BK];
  __shared__ __align__(16) bf16_t Bs[128 * BK];
  __shared__ __align__(16) bf16_t Tt[128 * TP];   // 34 KB staging tile
  int tid = threadIdx.x, wave = tid >> 6, lane = tid & 63;
  int l16 = lane & 15, quad = lane >> 4;
  // 2D XCD chunk: grid (32,24) -> 8 rectangles of 8x12 blocks, one per XCD.
  int id = blockIdx.y * 32 + blockIdx.x;
  int xcd = id & 7, local = id >> 3;          // local in [0,96)
  int bxi = (xcd & 3) * 8 + (local & 7);
  int byi = (xcd >> 2) * 12 + (local >> 3);
  int bm = bxi * 128, bn = byi * 128;
  int wm = (wave >> 1) * 64, wn = (wave & 1) * 64;
  int srow = wave * 32 + (lane >> 2);
  int scol = (lane & 3) * 8;
  const bf16_t* gA0 = &A [(size_t)(bm + srow)      * K + scol];
  const bf16_t* gA1 = &A [(size_t)(bm + srow + 16) * K + scol];
  const bf16_t* gB0 = &Bt[(size_t)(bn + srow)      * K + scol];
  const bf16_t* gB1 = &Bt[(size_t)(bn + srow + 16) * K + scol];
  bf16_t* lA0 = &As[(wave * 32)      * BK];
  bf16_t* lA1 = &As[(wave * 32 + 16) * BK];
  bf16_t* lB0 = &Bs[(wave * 32)      * BK];
  bf16_t* lB1 = &Bs[(wave * 32 + 16) * BK];
  f32x4 acc[4][4] = {};
  for (int k0 = 0; k0 < K; k0 += BK) {
    GLL16(gA0 + k0, lA0);
    GLL16(gA1 + k0, lA1);
    GLL16(gB0 + k0, lB0);
    GLL16(gB1 + k0, lB1);
    __syncthreads();
    bf16x8 af[4], bfr[4];
    #pragma unroll
    for (int t = 0; t < 4; ++t) {
      af[t]  = *(const bf16x8*)&As[(wm + t * 16 + l16) * BK + quad * 8];
      bfr[t] = *(const bf16x8*)&Bs[(wn + t * 16 + l16) * BK + quad * 8];
    }
    #pragma unroll
    for (int mt = 0; mt < 4; ++mt)
      #pragma unroll
      for (int nt = 0; nt < 4; ++nt)
        acc[mt][nt] = __builtin_amdgcn_mfma_f32_16x16x32_bf16(af[mt], bfr[nt], acc[mt][nt], 0, 0, 0);
    __syncthreads();
  }
  // ---- fused epilogue: stage into LDS, then coalesced bf16x8 flush ----
  if (byi < 16) {
    // Q or K: RoPE on fp32 acc; pairs (2j,2j+1) adjacent lanes -> shfl_xor(1).
    float qs = (byi < 8) ? QSCALE : 1.0f;
    bf16_t* dst = (byi < 8) ? Qb : Kb;
    #pragma unroll
    for (int mt = 0; mt < 4; ++mt)
      #pragma unroll
      for (int r = 0; r < 4; ++r) {
        int row_l = wm + mt * 16 + quad * 4 + r;
        int n = (bm + row_l) & 2047;
        const float* cr = tc + n * 32;
        const float* sr = ts + n * 32;
        #pragma unroll
        for (int nt = 0; nt < 4; ++nt) {
          int col_l = wn + nt * 16 + l16;
          int d = (bn + col_l) & 63, j = d >> 1;
          float val = acc[mt][nt][r];
          float p = __shfl_xor(val, 1);
          float c = cr[j], s = sr[j];
          float o = (d & 1) ? (val * c + p * s) : (val * c - p * s);
          Tt[row_l * TP + col_l] = (bf16_t)(o * qs);
        }
      }
    __syncthreads();
    // flush: 2048 bf16x8 chunks; 16 lanes per row -> 2x128B contiguous segments
    #pragma unroll
    for (int it = 0; it < 8; ++it) {
      int idx = tid + 256 * it;
      int row_l = idx >> 4, ck = (idx & 15) * 8;
      bf16x8 v = *(const bf16x8*)&Tt[row_l * TP + ck];
      int grow = bm + row_l, b = grow >> 11, n = grow & 2047;
      int col = bn + ck, h = (col >> 6) & 15, d = col & 63;
      *(bf16x8*)&dst[((size_t)(b * H_ + h) * N_ + n) * DH_ + d] = v;
    }
  } else {
    // V: stage transposed (Tt[col][row]) so flush rows are n-contiguous in Vb[bh][d][n].
    #pragma unroll
    for (int mt = 0; mt < 4; ++mt)
      #pragma unroll
      for (int nt = 0; nt < 4; ++nt) {
        int col_l = wn + nt * 16 + l16;
        int row0 = wm + mt * 16 + quad * 4;
        #pragma unroll
        for (int r = 0; r < 4; ++r)
          Tt[col_l * TP + row0 + r] = (bf16_t)acc[mt][nt][r];
      }
    __syncthreads();
    int b = bm >> 11, nb = bm & 2047;
    #pragma unroll
    for (int it = 0; it < 8; ++it) {
      int idx = tid + 256 * it;
      int col_l = idx >> 4, ck = (idx & 15) * 8;
      bf16x8 v = *(const bf16x8*)&Tt[col_l * TP + ck];
      int vcol = bn + col_l - 2048, h = vcol >> 6, d = vcol & 63;
      *(bf16x8*)&Vb[((size_t)(b * H_ + h) * DH_ + d) * N_ + nb + ck] = v;
    }
  }
}

// ---------------- GEMM: 128x64 tile (fp32 out) — for N=1024 out-proj ----------------
__global__ __launch_bounds__(256) void k_gemm_bt_n64(const bf16_t* __restrict__ A,
    const bf16_t* __restrict__ Bt, float* __restrict__ C, int M, int N, int K) {
  constexpr int BK = 32;
  __shared__ __align__(16) bf16_t As[128 * BK];
  __shared__ __align__(16) bf16_t Bs[64 * BK];
  int tid = threadIdx.x, wave = tid >> 6, lane = tid & 63;
  int l16 = lane & 15, quad = lane >> 4;
  int swz = xcd_swizzle_id();
  int bxi = swz % gridDim.x, byi = swz / gridDim.x;
  int bm = bxi * 128, bn = byi * 64;
  int wm = (wave >> 1) * 64, wn = (wave & 1) * 32;
  int srow = wave * 32 + (lane >> 2);
  int scol = (lane & 3) * 8;
  const bf16_t* gA0 = &A [(size_t)(bm + srow)      * K + scol];
  const bf16_t* gA1 = &A [(size_t)(bm + srow + 16) * K + scol];
  int srB = wave * 16 + (lane >> 2);
  const bf16_t* gB0 = &Bt[(size_t)(bn + srB) * K + scol];
  bf16_t* lA0 = &As[(wave * 32)      * BK];
  bf16_t* lA1 = &As[(wave * 32 + 16) * BK];
  bf16_t* lB0 = &Bs[(wave * 16)      * BK];
  f32x4 acc[4][2] = {};
  for (int k0 = 0; k0 < K; k0 += BK) {
    GLL16(gA0 + k0, lA0);
    GLL16(gA1 + k0, lA1);
    GLL16(gB0 + k0, lB0);
    __syncthreads();
    bf16x8 af[4], bfr[2];
    #pragma unroll
    for (int t = 0; t < 4; ++t)
      af[t]  = *(const bf16x8*)&As[(wm + t * 16 + l16) * BK + quad * 8];
    #pragma unroll
    for (int t = 0; t < 2; ++t)
      bfr[t] = *(const bf16x8*)&Bs[(wn + t * 16 + l16) * BK + quad * 8];
    #pragma unroll
    for (int mt = 0; mt < 4; ++mt)
      #pragma unroll
      for (int nt = 0; nt < 2; ++nt)
        acc[mt][nt] = __builtin_amdgcn_mfma_f32_16x16x32_bf16(af[mt], bfr[nt], acc[mt][nt], 0, 0, 0);
    __syncthreads();
  }
  #pragma unroll
  for (int mt = 0; mt < 4; ++mt)
    #pragma unroll
    for (int nt = 0; nt < 2; ++nt)
      #pragma unroll
      for (int r = 0; r < 4; ++r) {
        int row = bm + wm + mt * 16 + quad * 4 + r;
        int col = bn + wn + nt * 16 + l16;
        C[(size_t)row * N + col] = acc[mt][nt][r];
      }
}

// ---------------- flash attention: S^T form, fixed-max softmax, 32 q/wave ----------------
// v5 (measured 53.4 µs, MfmaUtil 28%, FETCH 12.8MB): XCD swizzle; softmax 2^x
// (log2e folded into Q-scale, -8*log2e into C-init); row-sum via ones-MFMA;
// dbuf K/V + async-STAGE + setprio; single barrier/tile.
__global__ __launch_bounds__(256) void k_flash(const bf16_t* __restrict__ Qb,
    const bf16_t* __restrict__ Kb, const bf16_t* __restrict__ Vb,
    const float* __restrict__ gsig, bf16_t* __restrict__ Ao) {
  __shared__ __align__(16) bf16_t Ks[2][64 * 72];    // [buf][key][dh], stride 72
  __shared__ __align__(16) bf16_t Vt[2][64 * 72];    // [buf][dh][key], stride 72
  __shared__ __align__(16) bf16_t Ps[4][32 * 72];    // per-wave [q][key], stride 72
  int swz = xcd_swizzle_id();                        // grid (16, 32): nwg=512, %8==0
  int qblk = swz & 15, bh = swz >> 4;
  int b = bh >> 4, h = bh & 15;
  int tid = threadIdx.x, wave = tid >> 6, lane = tid & 63;
  int l16 = lane & 15, quad = lane >> 4;
  int qw = qblk * 128 + wave * 32;
  const bf16_t* Qh = Qb + (size_t)bh * N_ * DH_;
  const bf16_t* Kh = Kb + (size_t)bh * N_ * DH_;
  const bf16_t* Vh = Vb + (size_t)bh * DH_ * N_;     // [64][2048]
  bf16_t* Pw = Ps[wave];
  bf16x8 qf[2][2];
  #pragma unroll
  for (int qt = 0; qt < 2; ++qt)
    #pragma unroll
    for (int hf = 0; hf < 2; ++hf)
      qf[qt][hf] = *(const bf16x8*)&Qh[(size_t)(qw + qt * 16 + l16) * DH_ + hf * 32 + quad * 8];
  bf16x8 onesf;
  #pragma unroll
  for (int i = 0; i < 8; ++i) onesf[i] = (bf16_t)1.0f;
  f32x4 accO[2][4] = {};
  f32x4 accL[2] = {};                // row-sum via ones-MFMA; same layout as accO
  int sk = tid >> 3;                 // 0..31
  int sc = (tid & 7) * 8;
  // ---- prologue: stage tile 0 into buf 0 ----
  bf16x8 rk0 = *(const bf16x8*)&Kh[(size_t)sk * DH_ + sc];
  bf16x8 rk1 = *(const bf16x8*)&Kh[(size_t)(sk + 32) * DH_ + sc];
  bf16x8 rv0 = *(const bf16x8*)&Vh[(size_t)sk * N_ + sc];
  bf16x8 rv1 = *(const bf16x8*)&Vh[(size_t)(sk + 32) * N_ + sc];
  *(bf16x8*)&Ks[0][sk * 72 + sc]        = rk0;
  *(bf16x8*)&Ks[0][(sk + 32) * 72 + sc] = rk1;
  *(bf16x8*)&Vt[0][sk * 72 + sc]        = rv0;
  *(bf16x8*)&Vt[0][(sk + 32) * 72 + sc] = rv1;
  __syncthreads();
  const f32x4 zinit = {NEGC, NEGC, NEGC, NEGC};
  for (int k0 = 0; k0 < N_; k0 += 64) {
    int cur = (k0 >> 6) & 1;
    const bf16_t* Kc = Ks[cur];
    const bf16_t* Vc = Vt[cur];
    int kn = k0 + 64;
    if (kn < N_) {
      rk0 = *(const bf16x8*)&Kh[(size_t)(kn + sk) * DH_ + sc];
      rk1 = *(const bf16x8*)&Kh[(size_t)(kn + sk + 32) * DH_ + sc];
      rv0 = *(const bf16x8*)&Vh[(size_t)sk * N_ + kn + sc];
      rv1 = *(const bf16x8*)&Vh[(size_t)(sk + 32) * N_ + kn + sc];
    }
    // S^T = K . Q^T -> C[key][q]; C-init = -8*log2e so st = log2e*(s-8)
    f32x4 st[4][2];
    __builtin_amdgcn_s_setprio(1);
    #pragma unroll
    for (int kt = 0; kt < 4; ++kt) {
      bf16x8 kf0 = *(const bf16x8*)&Kc[(kt * 16 + l16) * 72 + quad * 8];
      bf16x8 kf1 = *(const bf16x8*)&Kc[(kt * 16 + l16) * 72 + 32 + quad * 8];
      #pragma unroll
      for (int qt = 0; qt < 2; ++qt) {
        f32x4 z = zinit;
        z = __builtin_amdgcn_mfma_f32_16x16x32_bf16(kf0, qf[qt][0], z, 0, 0, 0);
        z = __builtin_amdgcn_mfma_f32_16x16x32_bf16(kf1, qf[qt][1], z, 0, 0, 0);
        st[kt][qt] = z;
      }
    }
    __builtin_amdgcn_s_setprio(0);
    // softmax: p = 2^st (bare v_exp_f32)
    #pragma unroll
    for (int qt = 0; qt < 2; ++qt)
      #pragma unroll
      for (int kt = 0; kt < 4; ++kt) {
        bf16x4 pk;
        #pragma unroll
        for (int r = 0; r < 4; ++r)
          pk[r] = (bf16_t)EXP2F(st[kt][qt][r]);
        *(bf16x4*)&Pw[(qt * 16 + l16) * 72 + kt * 16 + quad * 4] = pk;
      }
    // P fragments (A-operand) + PV; row-sum via ones-MFMA on the matrix pipe
    bf16x8 pf[2][2];
    #pragma unroll
    for (int qt = 0; qt < 2; ++qt)
      #pragma unroll
      for (int hf = 0; hf < 2; ++hf)
        pf[qt][hf] = *(const bf16x8*)&Pw[(qt * 16 + l16) * 72 + hf * 32 + quad * 8];
    __builtin_amdgcn_s_setprio(1);
    #pragma unroll
    for (int qt = 0; qt < 2; ++qt) {
      accL[qt] = __builtin_amdgcn_mfma_f32_16x16x32_bf16(pf[qt][0], onesf, accL[qt], 0, 0, 0);
      accL[qt] = __builtin_amdgcn_mfma_f32_16x16x32_bf16(pf[qt][1], onesf, accL[qt], 0, 0, 0);
    }
    #pragma unroll
    for (int dt = 0; dt < 4; ++dt)
      #pragma unroll
      for (int hf = 0; hf < 2; ++hf) {
        bf16x8 vf = *(const bf16x8*)&Vc[(dt * 16 + l16) * 72 + hf * 32 + quad * 8];
        #pragma unroll
        for (int qt = 0; qt < 2; ++qt)
          accO[qt][dt] = __builtin_amdgcn_mfma_f32_16x16x32_bf16(pf[qt][hf], vf, accO[qt][dt], 0, 0, 0);
      }
    __builtin_amdgcn_s_setprio(0);
    if (kn < N_) {
      int nb = cur ^ 1;
      *(bf16x8*)&Ks[nb][sk * 72 + sc]        = rk0;
      *(bf16x8*)&Ks[nb][(sk + 32) * 72 + sc] = rk1;
      *(bf16x8*)&Vt[nb][sk * 72 + sc]        = rv0;
      *(bf16x8*)&Vt[nb][(sk + 32) * 72 + sc] = rv1;
    }
    __syncthreads();
  }
  // epilogue: O and L are both in C layout (q = qt*16+quad*4+r, d = dt*16+l16)
  #pragma unroll
  for (int qt = 0; qt < 2; ++qt)
    #pragma unroll
    for (int r = 0; r < 4; ++r) {
      int q = qw + qt * 16 + quad * 4 + r;
      float g = gsig[((size_t)b * N_ + q) * H_ + h];
      float ginv = g / accL[qt][r];
      #pragma unroll
      for (int dt = 0; dt < 4; ++dt)
        Ao[((size_t)b * N_ + q) * (H_ * DH_) + h * DH_ + dt * 16 + l16] =
            (bf16_t)(accO[qt][dt][r] * ginv);
    }
}

extern "C" void kernel_launch(void* const* d_in, const int* in_sizes, int n_in,
                              void* d_out, int out_size, void* d_ws, size_t ws_size,
                              hipStream_t stream) {
  (void)in_sizes; (void)n_in; (void)out_size; (void)ws_size;
  const float* x      = (const float*)d_in[0];
  const float* gamma  = (const float*)d_in[1];
  const float* w_qkv  = (const float*)d_in[2];
  const float* w_gate = (const float*)d_in[3];
  const float* b_gate = (const float*)d_in[4];
  const float* w_out  = (const float*)d_in[5];
  const float* freqs  = (const float*)d_in[6];
  float* out = (float*)d_out;
  char* ws = (char*)d_ws;
  bf16_t* xn    = (bf16_t*)(ws);                          // 8 MB
  bf16_t* wqkvT = (bf16_t*)(ws + ((size_t)8  << 20));     // 6 MB
  bf16_t* woutT = (bf16_t*)(ws + ((size_t)14 << 20));     // 2 MB
  bf16_t* Qb    = (bf16_t*)(ws + ((size_t)16 << 20));     // 8 MB [bh][n][64]
  bf16_t* Kb    = (bf16_t*)(ws + ((size_t)24 << 20));     // 8 MB [bh][n][64]
  bf16_t* Vb    = (bf16_t*)(ws + ((size_t)32 << 20));     // 8 MB [bh][64][n]
  float*  gsig  = (float*) (ws + ((size_t)40 << 20));     // 256 KB
  bf16_t* attn  = (bf16_t*)(ws + ((size_t)41 << 20));     // 8 MB
  float*  trigc = (float*) (ws + ((size_t)49 << 20));     // 256 KB
  float*  trigs = (float*) (ws + ((size_t)50 << 20));     // 256 KB

  k_trig<<<256, 256, 0, stream>>>(freqs, trigc, trigs);
  k_transpose_cvt<<<dim3(3072 / 32, 1024 / 32), 256, 0, stream>>>(w_qkv, wqkvT, 1024, 3072);
  k_transpose_cvt<<<dim3(1024 / 32, 1024 / 32), 256, 0, stream>>>(w_out, woutT, 1024, 1024);
  k_rmsnorm_gates<<<4096, 256, 0, stream>>>(x, gamma, w_gate, b_gate, xn, gsig);
  k_gemm_qkv<<<dim3(32, 24), 256, 0, stream>>>(xn, wqkvT, trigc, trigs, Qb, Kb, Vb);
  k_flash<<<dim3(16, 32), 256, 0, stream>>>(Qb, Kb, Vb, gsig, attn);
  k_gemm_bt_n64<<<dim3(32, 16), 256, 0, stream>>>(attn, woutT, out, 4096, 1024, 1024);
}

// Round 12
// 224.926 us; speedup vs baseline: 1.0779x; 1.0657x over previous
//
#include <hip/hip_runtime.h>

typedef __bf16 bf16_t;
typedef __bf16 bf16x8 __attribute__((ext_vector_type(8)));
typedef __bf16 bf16x4 __attribute__((ext_vector_type(4)));
typedef float f32x4 __attribute__((ext_vector_type(4)));

#define B_  2
#define N_  2048
#define D_  1024
#define H_  16
#define DH_ 64

// Q pre-scale: (1/sqrt(64)) * log2(e) so softmax can use raw v_exp_f32 (2^x)
#define QSCALE 0.18033688011112042f
// 8 * log2(e): folded into QK^T accumulator init => st = log2e*(s - 8)
#define NEGC  -11.541560327111707f

#if __has_builtin(__builtin_amdgcn_exp2f)
#define EXP2F(x) __builtin_amdgcn_exp2f(x)
#else
#define EXP2F(x) exp2f(x)
#endif

#define GLL16(g, l) __builtin_amdgcn_global_load_lds( \
    (const __attribute__((address_space(1))) void*)(g), \
    (__attribute__((address_space(3))) void*)(l), 16, 0, 0)

// XCD-aware chunked swizzle (T1). Requires nwg % 8 == 0.
__device__ __forceinline__ int xcd_swizzle_id() {
  int id = blockIdx.y * gridDim.x + blockIdx.x;
  int cpx = (gridDim.x * gridDim.y) >> 3;
  return (id & 7) * cpx + (id >> 3);
}

// ---------------- fused prep: rmsnorm+gates | w_qkv^T | w_out^T | trig table ----------------
// All four sections are data-independent; block-uniform branch on flattened id.
// ids: [0,4096) rmsnorm row | [4096,7168) w_qkv transpose | [7168,8192) w_out transpose
//      | [8192,8448) trig.
__global__ __launch_bounds__(256) void k_prep(
    const float* __restrict__ x, const float* __restrict__ gamma,
    const float* __restrict__ wg, const float* __restrict__ bg,
    bf16_t* __restrict__ xn, float* __restrict__ gsig,
    const float* __restrict__ w_qkv, bf16_t* __restrict__ wqkvT,
    const float* __restrict__ w_out, bf16_t* __restrict__ woutT,
    const float* __restrict__ freqs, float* __restrict__ tc, float* __restrict__ ts) {
  __shared__ __align__(16) char smem_raw[17424];   // max(rmsnorm 17.4KB, transpose 4.2KB)
  int id = blockIdx.x, tid = threadIdx.x;
  if (id < 4096) {
    // ---- RMSNorm + fused gates, row = id ----
    float* red4 = (float*)smem_raw;
    float (*red)[17] = (float(*)[17])(smem_raw + 16);
    int row = id;
    const float4* xr = (const float4*)(x + (size_t)row * D_);
    float4 v = xr[tid];
    float ss = v.x*v.x + v.y*v.y + v.z*v.z + v.w*v.w;
    #pragma unroll
    for (int off = 32; off > 0; off >>= 1) ss += __shfl_down(ss, off);
    if ((tid & 63) == 0) red4[tid >> 6] = ss;
    __syncthreads();
    float scale = 32.0f * rsqrtf(red4[0] + red4[1] + red4[2] + red4[3]);
    float4 g = ((const float4*)gamma)[tid];
    bf16x4 o;
    o[0] = (bf16_t)(v.x * scale * g.x);
    o[1] = (bf16_t)(v.y * scale * g.y);
    o[2] = (bf16_t)(v.z * scale * g.z);
    o[3] = (bf16_t)(v.w * scale * g.w);
    *(bf16x4*)(xn + (size_t)row * D_ + tid * 4) = o;
    float xv[4] = {(float)o[0], (float)o[1], (float)o[2], (float)o[3]};
    float part[16];
    #pragma unroll
    for (int h = 0; h < 16; ++h) part[h] = 0.f;
    #pragma unroll
    for (int j = 0; j < 4; ++j) {
      const float4* wr = (const float4*)&wg[(size_t)(tid * 4 + j) * 16];
      #pragma unroll
      for (int q = 0; q < 4; ++q) {
        float4 w4 = wr[q];
        part[q * 4 + 0] += xv[j] * w4.x;
        part[q * 4 + 1] += xv[j] * w4.y;
        part[q * 4 + 2] += xv[j] * w4.z;
        part[q * 4 + 3] += xv[j] * w4.w;
      }
    }
    #pragma unroll
    for (int h = 0; h < 16; ++h) red[tid][h] = part[h];
    __syncthreads();
    int h = tid & 15, grp = tid >> 4;
    float s = 0.f;
    #pragma unroll
    for (int k = 0; k < 16; ++k) s += red[grp * 16 + k][h];
    __syncthreads();
    red[grp][h] = s;
    __syncthreads();
    if (tid < 16) {
      float acc = bg[tid];
      #pragma unroll
      for (int k = 0; k < 16; ++k) acc += red[k][tid];
      gsig[(size_t)row * 16 + tid] = 1.0f / (1.0f + __expf(-acc));
    }
  } else if (id < 8192) {
    // ---- weight transpose fp32 [R][C] -> bf16 [C][R] ----
    const float* W; bf16_t* Wt; int R, C, bx, by;
    if (id < 7168) { int local = id - 4096; W = w_qkv; Wt = wqkvT; R = 1024; C = 3072;
                     bx = local % 96; by = local / 96; }
    else           { int local = id - 7168; W = w_out; Wt = woutT; R = 1024; C = 1024;
                     bx = local & 31; by = local >> 5; }
    float (*tile)[33] = (float(*)[33])smem_raw;
    int c0 = bx * 32, r0 = by * 32;
    int tx = tid & 31, ty = tid >> 5;
    #pragma unroll
    for (int i = 0; i < 4; ++i) {
      int r = ty + i * 8;
      tile[r][tx] = W[(size_t)(r0 + r) * C + c0 + tx];
    }
    __syncthreads();
    #pragma unroll
    for (int i = 0; i < 4; ++i) {
      int rr = ty + i * 8;
      Wt[(size_t)(c0 + rr) * R + r0 + tx] = (bf16_t)tile[tx][rr];
    }
  } else {
    // ---- trig table: tc/ts[n][j] = cos/sin(n*freqs[j]) ----
    int idx = (id - 8192) * 256 + tid;   // 65536 total
    int n = idx >> 5, j = idx & 31;
    float f = (float)n * freqs[j];
    tc[idx] = cosf(f);
    ts[idx] = sinf(f);
  }
}

// ---------------- QKV GEMM: dbuf K-loop + fused RoPE + LDS-staged epilogue ----------------
// v3 (v2 measured 67.9us, MfmaUtil 14%, all pipes idle -> latency-bound on the
// per-iter vmcnt(0)+2-barrier drain at 3 blocks/CU, 32 K-iters):
//  - double-buffered As/Bs, GLL16 for tile t+1 issued BEFORE computing tile t,
//    ONE barrier per iter (flash-v2-proven pattern). Drain at barrier now waits on
//    loads that aged through the whole MFMA phase.
//  - LDS union keeps footprint at 34KB: [As0|As1|Bs0|Bs1] 32KB during loop, Tt after.
// Epilogue + 2D XCD chunk unchanged from v2 (FETCH 30MB verified).
__global__ __launch_bounds__(256) void k_gemm_qkv(const bf16_t* __restrict__ A,
    const bf16_t* __restrict__ Bt, const float* __restrict__ tc,
    const float* __restrict__ ts, bf16_t* __restrict__ Qb,
    bf16_t* __restrict__ Kb, bf16_t* __restrict__ Vb) {
  constexpr int BK = 32, K = 1024;
  constexpr int TP = 136;                         // Tt stride (pad 8 bf16)
  __shared__ __align__(16) char smem[128 * TP * 2];   // 34816 B union
  bf16_t* As0 = (bf16_t*)smem;                    // buf1 = +4096 elems
  bf16_t* Bs0 = (bf16_t*)(smem + 16384);          // buf1 = +4096 elems
  bf16_t* Tt  = (bf16_t*)smem;                    // epilogue staging (aliases all)
  int tid = threadIdx.x, wave = tid >> 6, lane = tid & 63;
  int l16 = lane & 15, quad = lane >> 4;
  // 2D XCD chunk: grid (32,24) -> 8 rectangles of 8x12 blocks, one per XCD.
  int id = blockIdx.y * 32 + blockIdx.x;
  int xcd = id & 7, local = id >> 3;
  int bxi = (xcd & 3) * 8 + (local & 7);
  int byi = (xcd >> 2) * 12 + (local >> 3);
  int bm = bxi * 128, bn = byi * 128;
  int wm = (wave >> 1) * 64, wn = (wave & 1) * 64;
  int srow = wave * 32 + (lane >> 2);
  int scol = (lane & 3) * 8;
  const bf16_t* gA0 = &A [(size_t)(bm + srow)      * K + scol];
  const bf16_t* gA1 = &A [(size_t)(bm + srow + 16) * K + scol];
  const bf16_t* gB0 = &Bt[(size_t)(bn + srow)      * K + scol];
  const bf16_t* gB1 = &Bt[(size_t)(bn + srow + 16) * K + scol];
  bf16_t* lA0 = &As0[(wave * 32)      * BK];      // wave-uniform bases (buf0)
  bf16_t* lA1 = &As0[(wave * 32 + 16) * BK];
  bf16_t* lB0 = &Bs0[(wave * 32)      * BK];
  bf16_t* lB1 = &Bs0[(wave * 32 + 16) * BK];
  f32x4 acc[4][4] = {};
  // prologue: stage tile 0 into buf 0
  GLL16(gA0, lA0); GLL16(gA1, lA1); GLL16(gB0, lB0); GLL16(gB1, lB1);
  __syncthreads();
  for (int k0 = 0; k0 < K; k0 += BK) {
    int cur = (k0 >> 5) & 1;
    int co  = cur * 4096;                 // current buffer elem offset
    int nxt = 4096 - co;                  // next buffer (cur^1) elem offset
    if (k0 + BK < K) {                    // issue next tile BEFORE compute
      GLL16(gA0 + k0 + BK, lA0 + nxt);
      GLL16(gA1 + k0 + BK, lA1 + nxt);
      GLL16(gB0 + k0 + BK, lB0 + nxt);
      GLL16(gB1 + k0 + BK, lB1 + nxt);
    }
    const bf16_t* Asc = As0 + co;
    const bf16_t* Bsc = Bs0 + co;
    bf16x8 af[4], bfr[4];
    #pragma unroll
    for (int t = 0; t < 4; ++t) {
      af[t]  = *(const bf16x8*)&Asc[(wm + t * 16 + l16) * BK + quad * 8];
      bfr[t] = *(const bf16x8*)&Bsc[(wn + t * 16 + l16) * BK + quad * 8];
    }
    #pragma unroll
    for (int mt = 0; mt < 4; ++mt)
      #pragma unroll
      for (int nt = 0; nt < 4; ++nt)
        acc[mt][nt] = __builtin_amdgcn_mfma_f32_16x16x32_bf16(af[mt], bfr[nt], acc[mt][nt], 0, 0, 0);
    __syncthreads();   // single barrier: fences buf[cur] reads + drains buf[cur^1] loads
  }
  // ---- fused epilogue: stage into Tt (aliases As/Bs, safe after final barrier) ----
  if (byi < 16) {
    // Q or K: RoPE on fp32 acc; pairs (2j,2j+1) adjacent lanes -> shfl_xor(1).
    float qs = (byi < 8) ? QSCALE : 1.0f;
    bf16_t* dst = (byi < 8) ? Qb : Kb;
    #pragma unroll
    for (int mt = 0; mt < 4; ++mt)
      #pragma unroll
      for (int r = 0; r < 4; ++r) {
        int row_l = wm + mt * 16 + quad * 4 + r;
        int n = (bm + row_l) & 2047;
        const float* cr = tc + n * 32;
        const float* sr = ts + n * 32;
        #pragma unroll
        for (int nt = 0; nt < 4; ++nt) {
          int col_l = wn + nt * 16 + l16;
          int d = (bn + col_l) & 63, j = d >> 1;
          float val = acc[mt][nt][r];
          float p = __shfl_xor(val, 1);
          float c = cr[j], s = sr[j];
          float o = (d & 1) ? (val * c + p * s) : (val * c - p * s);
          Tt[row_l * TP + col_l] = (bf16_t)(o * qs);
        }
      }
    __syncthreads();
    #pragma unroll
    for (int it = 0; it < 8; ++it) {
      int idx = tid + 256 * it;
      int row_l = idx >> 4, ck = (idx & 15) * 8;
      bf16x8 v = *(const bf16x8*)&Tt[row_l * TP + ck];
      int grow = bm + row_l, b = grow >> 11, n = grow & 2047;
      int col = bn + ck, h = (col >> 6) & 15, d = col & 63;
      *(bf16x8*)&dst[((size_t)(b * H_ + h) * N_ + n) * DH_ + d] = v;
    }
  } else {
    // V: stage transposed (Tt[col][row]) so flush rows are n-contiguous in Vb[bh][d][n].
    #pragma unroll
    for (int mt = 0; mt < 4; ++mt)
      #pragma unroll
      for (int nt = 0; nt < 4; ++nt) {
        int col_l = wn + nt * 16 + l16;
        int row0 = wm + mt * 16 + quad * 4;
        #pragma unroll
        for (int r = 0; r < 4; ++r)
          Tt[col_l * TP + row0 + r] = (bf16_t)acc[mt][nt][r];
      }
    __syncthreads();
    int b = bm >> 11, nb = bm & 2047;
    #pragma unroll
    for (int it = 0; it < 8; ++it) {
      int idx = tid + 256 * it;
      int col_l = idx >> 4, ck = (idx & 15) * 8;
      bf16x8 v = *(const bf16x8*)&Tt[col_l * TP + ck];
      int vcol = bn + col_l - 2048, h = vcol >> 6, d = vcol & 63;
      *(bf16x8*)&Vb[((size_t)(b * H_ + h) * DH_ + d) * N_ + nb + ck] = v;
    }
  }
}

// ---------------- GEMM: 128x64 tile (fp32 out) — for N=1024 out-proj ----------------
__global__ __launch_bounds__(256) void k_gemm_bt_n64(const bf16_t* __restrict__ A,
    const bf16_t* __restrict__ Bt, float* __restrict__ C, int M, int N, int K) {
  constexpr int BK = 32;
  __shared__ __align__(16) bf16_t As[128 * BK];
  __shared__ __align__(16) bf16_t Bs[64 * BK];
  int tid = threadIdx.x, wave = tid >> 6, lane = tid & 63;
  int l16 = lane & 15, quad = lane >> 4;
  int swz = xcd_swizzle_id();
  int bxi = swz % gridDim.x, byi = swz / gridDim.x;
  int bm = bxi * 128, bn = byi * 64;
  int wm = (wave >> 1) * 64, wn = (wave & 1) * 32;
  int srow = wave * 32 + (lane >> 2);
  int scol = (lane & 3) * 8;
  const bf16_t* gA0 = &A [(size_t)(bm + srow)      * K + scol];
  const bf16_t* gA1 = &A [(size_t)(bm + srow + 16) * K + scol];
  int srB = wave * 16 + (lane >> 2);
  const bf16_t* gB0 = &Bt[(size_t)(bn + srB) * K + scol];
  bf16_t* lA0 = &As[(wave * 32)      * BK];
  bf16_t* lA1 = &As[(wave * 32 + 16) * BK];
  bf16_t* lB0 = &Bs[(wave * 16)      * BK];
  f32x4 acc[4][2] = {};
  for (int k0 = 0; k0 < K; k0 += BK) {
    GLL16(gA0 + k0, lA0);
    GLL16(gA1 + k0, lA1);
    GLL16(gB0 + k0, lB0);
    __syncthreads();
    bf16x8 af[4], bfr[2];
    #pragma unroll
    for (int t = 0; t < 4; ++t)
      af[t]  = *(const bf16x8*)&As[(wm + t * 16 + l16) * BK + quad * 8];
    #pragma unroll
    for (int t = 0; t < 2; ++t)
      bfr[t] = *(const bf16x8*)&Bs[(wn + t * 16 + l16) * BK + quad * 8];
    #pragma unroll
    for (int mt = 0; mt < 4; ++mt)
      #pragma unroll
      for (int nt = 0; nt < 2; ++nt)
        acc[mt][nt] = __builtin_amdgcn_mfma_f32_16x16x32_bf16(af[mt], bfr[nt], acc[mt][nt], 0, 0, 0);
    __syncthreads();
  }
  #pragma unroll
  for (int mt = 0; mt < 4; ++mt)
    #pragma unroll
    for (int nt = 0; nt < 2; ++nt)
      #pragma unroll
      for (int r = 0; r < 4; ++r) {
        int row = bm + wm + mt * 16 + quad * 4 + r;
        int col = bn + wn + nt * 16 + l16;
        C[(size_t)row * N + col] = acc[mt][nt][r];
      }
}

// ---------------- flash attention: S^T form, fixed-max softmax, 32 q/wave ----------------
// v5 (measured 53.4 µs, MfmaUtil 28%, FETCH 12.8MB): XCD swizzle; softmax 2^x;
// row-sum via ones-MFMA; dbuf K/V + async-STAGE + setprio; single barrier/tile.
__global__ __launch_bounds__(256) void k_flash(const bf16_t* __restrict__ Qb,
    const bf16_t* __restrict__ Kb, const bf16_t* __restrict__ Vb,
    const float* __restrict__ gsig, bf16_t* __restrict__ Ao) {
  __shared__ __align__(16) bf16_t Ks[2][64 * 72];    // [buf][key][dh], stride 72
  __shared__ __align__(16) bf16_t Vt[2][64 * 72];    // [buf][dh][key], stride 72
  __shared__ __align__(16) bf16_t Ps[4][32 * 72];    // per-wave [q][key], stride 72
  int swz = xcd_swizzle_id();                        // grid (16, 32): nwg=512, %8==0
  int qblk = swz & 15, bh = swz >> 4;
  int b = bh >> 4, h = bh & 15;
  int tid = threadIdx.x, wave = tid >> 6, lane = tid & 63;
  int l16 = lane & 15, quad = lane >> 4;
  int qw = qblk * 128 + wave * 32;
  const bf16_t* Qh = Qb + (size_t)bh * N_ * DH_;
  const bf16_t* Kh = Kb + (size_t)bh * N_ * DH_;
  const bf16_t* Vh = Vb + (size_t)bh * DH_ * N_;     // [64][2048]
  bf16_t* Pw = Ps[wave];
  bf16x8 qf[2][2];
  #pragma unroll
  for (int qt = 0; qt < 2; ++qt)
    #pragma unroll
    for (int hf = 0; hf < 2; ++hf)
      qf[qt][hf] = *(const bf16x8*)&Qh[(size_t)(qw + qt * 16 + l16) * DH_ + hf * 32 + quad * 8];
  bf16x8 onesf;
  #pragma unroll
  for (int i = 0; i < 8; ++i) onesf[i] = (bf16_t)1.0f;
  f32x4 accO[2][4] = {};
  f32x4 accL[2] = {};                // row-sum via ones-MFMA; same layout as accO
  int sk = tid >> 3;                 // 0..31
  int sc = (tid & 7) * 8;
  // ---- prologue: stage tile 0 into buf 0 ----
  bf16x8 rk0 = *(const bf16x8*)&Kh[(size_t)sk * DH_ + sc];
  bf16x8 rk1 = *(const bf16x8*)&Kh[(size_t)(sk + 32) * DH_ + sc];
  bf16x8 rv0 = *(const bf16x8*)&Vh[(size_t)sk * N_ + sc];
  bf16x8 rv1 = *(const bf16x8*)&Vh[(size_t)(sk + 32) * N_ + sc];
  *(bf16x8*)&Ks[0][sk * 72 + sc]        = rk0;
  *(bf16x8*)&Ks[0][(sk + 32) * 72 + sc] = rk1;
  *(bf16x8*)&Vt[0][sk * 72 + sc]        = rv0;
  *(bf16x8*)&Vt[0][(sk + 32) * 72 + sc] = rv1;
  __syncthreads();
  const f32x4 zinit = {NEGC, NEGC, NEGC, NEGC};
  for (int k0 = 0; k0 < N_; k0 += 64) {
    int cur = (k0 >> 6) & 1;
    const bf16_t* Kc = Ks[cur];
    const bf16_t* Vc = Vt[cur];
    int kn = k0 + 64;
    if (kn < N_) {
      rk0 = *(const bf16x8*)&Kh[(size_t)(kn + sk) * DH_ + sc];
      rk1 = *(const bf16x8*)&Kh[(size_t)(kn + sk + 32) * DH_ + sc];
      rv0 = *(const bf16x8*)&Vh[(size_t)sk * N_ + kn + sc];
      rv1 = *(const bf16x8*)&Vh[(size_t)(sk + 32) * N_ + kn + sc];
    }
    // S^T = K . Q^T -> C[key][q]; C-init = -8*log2e so st = log2e*(s-8)
    f32x4 st[4][2];
    __builtin_amdgcn_s_setprio(1);
    #pragma unroll
    for (int kt = 0; kt < 4; ++kt) {
      bf16x8 kf0 = *(const bf16x8*)&Kc[(kt * 16 + l16) * 72 + quad * 8];
      bf16x8 kf1 = *(const bf16x8*)&Kc[(kt * 16 + l16) * 72 + 32 + quad * 8];
      #pragma unroll
      for (int qt = 0; qt < 2; ++qt) {
        f32x4 z = zinit;
        z = __builtin_amdgcn_mfma_f32_16x16x32_bf16(kf0, qf[qt][0], z, 0, 0, 0);
        z = __builtin_amdgcn_mfma_f32_16x16x32_bf16(kf1, qf[qt][1], z, 0, 0, 0);
        st[kt][qt] = z;
      }
    }
    __builtin_amdgcn_s_setprio(0);
    // softmax: p = 2^st (bare v_exp_f32)
    #pragma unroll
    for (int qt = 0; qt < 2; ++qt)
      #pragma unroll
      for (int kt = 0; kt < 4; ++kt) {
        bf16x4 pk;
        #pragma unroll
        for (int r = 0; r < 4; ++r)
          pk[r] = (bf16_t)EXP2F(st[kt][qt][r]);
        *(bf16x4*)&Pw[(qt * 16 + l16) * 72 + kt * 16 + quad * 4] = pk;
      }
    // P fragments (A-operand) + PV; row-sum via ones-MFMA on the matrix pipe
    bf16x8 pf[2][2];
    #pragma unroll
    for (int qt = 0; qt < 2; ++qt)
      #pragma unroll
      for (int hf = 0; hf < 2; ++hf)
        pf[qt][hf] = *(const bf16x8*)&Pw[(qt * 16 + l16) * 72 + hf * 32 + quad * 8];
    __builtin_amdgcn_s_setprio(1);
    #pragma unroll
    for (int qt = 0; qt < 2; ++qt) {
      accL[qt] = __builtin_amdgcn_mfma_f32_16x16x32_bf16(pf[qt][0], onesf, accL[qt], 0, 0, 0);
      accL[qt] = __builtin_amdgcn_mfma_f32_16x16x32_bf16(pf[qt][1], onesf, accL[qt], 0, 0, 0);
    }
    #pragma unroll
    for (int dt = 0; dt < 4; ++dt)
      #pragma unroll
      for (int hf = 0; hf < 2; ++hf) {
        bf16x8 vf = *(const bf16x8*)&Vc[(dt * 16 + l16) * 72 + hf * 32 + quad * 8];
        #pragma unroll
        for (int qt = 0; qt < 2; ++qt)
          accO[qt][dt] = __builtin_amdgcn_mfma_f32_16x16x32_bf16(pf[qt][hf], vf, accO[qt][dt], 0, 0, 0);
      }
    __builtin_amdgcn_s_setprio(0);
    if (kn < N_) {
      int nb = cur ^ 1;
      *(bf16x8*)&Ks[nb][sk * 72 + sc]        = rk0;
      *(bf16x8*)&Ks[nb][(sk + 32) * 72 + sc] = rk1;
      *(bf16x8*)&Vt[nb][sk * 72 + sc]        = rv0;
      *(bf16x8*)&Vt[nb][(sk + 32) * 72 + sc] = rv1;
    }
    __syncthreads();
  }
  // epilogue: O and L are both in C layout (q = qt*16+quad*4+r, d = dt*16+l16)
  #pragma unroll
  for (int qt = 0; qt < 2; ++qt)
    #pragma unroll
    for (int r = 0; r < 4; ++r) {
      int q = qw + qt * 16 + quad * 4 + r;
      float g = gsig[((size_t)b * N_ + q) * H_ + h];
      float ginv = g / accL[qt][r];
      #pragma unroll
      for (int dt = 0; dt < 4; ++dt)
        Ao[((size_t)b * N_ + q) * (H_ * DH_) + h * DH_ + dt * 16 + l16] =
            (bf16_t)(accO[qt][dt][r] * ginv);
    }
}

extern "C" void kernel_launch(void* const* d_in, const int* in_sizes, int n_in,
                              void* d_out, int out_size, void* d_ws, size_t ws_size,
                              hipStream_t stream) {
  (void)in_sizes; (void)n_in; (void)out_size; (void)ws_size;
  const float* x      = (const float*)d_in[0];
  const float* gamma  = (const float*)d_in[1];
  const float* w_qkv  = (const float*)d_in[2];
  const float* w_gate = (const float*)d_in[3];
  const float* b_gate = (const float*)d_in[4];
  const float* w_out  = (const float*)d_in[5];
  const float* freqs  = (const float*)d_in[6];
  float* out = (float*)d_out;
  char* ws = (char*)d_ws;
  bf16_t* xn    = (bf16_t*)(ws);                          // 8 MB
  bf16_t* wqkvT = (bf16_t*)(ws + ((size_t)8  << 20));     // 6 MB
  bf16_t* woutT = (bf16_t*)(ws + ((size_t)14 << 20));     // 2 MB
  bf16_t* Qb    = (bf16_t*)(ws + ((size_t)16 << 20));     // 8 MB [bh][n][64]
  bf16_t* Kb    = (bf16_t*)(ws + ((size_t)24 << 20));     // 8 MB [bh][n][64]
  bf16_t* Vb    = (bf16_t*)(ws + ((size_t)32 << 20));     // 8 MB [bh][64][n]
  float*  gsig  = (float*) (ws + ((size_t)40 << 20));     // 256 KB
  bf16_t* attn  = (bf16_t*)(ws + ((size_t)41 << 20));     // 8 MB
  float*  trigc = (float*) (ws + ((size_t)49 << 20));     // 256 KB
  float*  trigs = (float*) (ws + ((size_t)50 << 20));     // 256 KB

  k_prep<<<8448, 256, 0, stream>>>(x, gamma, w_gate, b_gate, xn, gsig,
                                   w_qkv, wqkvT, w_out, woutT, freqs, trigc, trigs);
  k_gemm_qkv<<<dim3(32, 24), 256, 0, stream>>>(xn, wqkvT, trigc, trigs, Qb, Kb, Vb);
  k_flash<<<dim3(16, 32), 256, 0, stream>>>(Qb, Kb, Vb, gsig, attn);
  k_gemm_bt_n64<<<dim3(32, 16), 256, 0, stream>>>(attn, woutT, out, 4096, 1024, 1024);
}

// Round 13
// 219.568 us; speedup vs baseline: 1.1042x; 1.0244x over previous
//
#include <hip/hip_runtime.h>

typedef __bf16 bf16_t;
typedef __bf16 bf16x8 __attribute__((ext_vector_type(8)));
typedef __bf16 bf16x4 __attribute__((ext_vector_type(4)));
typedef float f32x4 __attribute__((ext_vector_type(4)));

#define B_  2
#define N_  2048
#define D_  1024
#define H_  16
#define DH_ 64

// Q pre-scale: (1/sqrt(64)) * log2(e) so softmax can use raw v_exp_f32 (2^x)
#define QSCALE 0.18033688011112042f
// 8 * log2(e): folded into QK^T accumulator init => st = log2e*(s - 8)
#define NEGC  -11.541560327111707f

#if __has_builtin(__builtin_amdgcn_exp2f)
#define EXP2F(x) __builtin_amdgcn_exp2f(x)
#else
#define EXP2F(x) exp2f(x)
#endif

#define GLL16(g, l) __builtin_amdgcn_global_load_lds( \
    (const __attribute__((address_space(1))) void*)(g), \
    (__attribute__((address_space(3))) void*)(l), 16, 0, 0)

// XCD-aware chunked swizzle (T1). Requires nwg % 8 == 0.
__device__ __forceinline__ int xcd_swizzle_id() {
  int id = blockIdx.y * gridDim.x + blockIdx.x;
  int cpx = (gridDim.x * gridDim.y) >> 3;
  return (id & 7) * cpx + (id >> 3);
}

// ---------------- fused prep: rmsnorm+gates | w_qkv^T | w_out^T | trig table ----------------
// All four sections are data-independent; block-uniform branch on flattened id.
// ids: [0,4096) rmsnorm row | [4096,7168) w_qkv transpose | [7168,8192) w_out transpose
//      | [8192,8448) trig.
__global__ __launch_bounds__(256) void k_prep(
    const float* __restrict__ x, const float* __restrict__ gamma,
    const float* __restrict__ wg, const float* __restrict__ bg,
    bf16_t* __restrict__ xn, float* __restrict__ gsig,
    const float* __restrict__ w_qkv, bf16_t* __restrict__ wqkvT,
    const float* __restrict__ w_out, bf16_t* __restrict__ woutT,
    const float* __restrict__ freqs, float* __restrict__ tc, float* __restrict__ ts) {
  __shared__ __align__(16) char smem_raw[17424];   // max(rmsnorm 17.4KB, transpose 4.2KB)
  int id = blockIdx.x, tid = threadIdx.x;
  if (id < 4096) {
    // ---- RMSNorm + fused gates, row = id ----
    float* red4 = (float*)smem_raw;
    float (*red)[17] = (float(*)[17])(smem_raw + 16);
    int row = id;
    const float4* xr = (const float4*)(x + (size_t)row * D_);
    float4 v = xr[tid];
    float ss = v.x*v.x + v.y*v.y + v.z*v.z + v.w*v.w;
    #pragma unroll
    for (int off = 32; off > 0; off >>= 1) ss += __shfl_down(ss, off);
    if ((tid & 63) == 0) red4[tid >> 6] = ss;
    __syncthreads();
    float scale = 32.0f * rsqrtf(red4[0] + red4[1] + red4[2] + red4[3]);
    float4 g = ((const float4*)gamma)[tid];
    bf16x4 o;
    o[0] = (bf16_t)(v.x * scale * g.x);
    o[1] = (bf16_t)(v.y * scale * g.y);
    o[2] = (bf16_t)(v.z * scale * g.z);
    o[3] = (bf16_t)(v.w * scale * g.w);
    *(bf16x4*)(xn + (size_t)row * D_ + tid * 4) = o;
    float xv[4] = {(float)o[0], (float)o[1], (float)o[2], (float)o[3]};
    float part[16];
    #pragma unroll
    for (int h = 0; h < 16; ++h) part[h] = 0.f;
    #pragma unroll
    for (int j = 0; j < 4; ++j) {
      const float4* wr = (const float4*)&wg[(size_t)(tid * 4 + j) * 16];
      #pragma unroll
      for (int q = 0; q < 4; ++q) {
        float4 w4 = wr[q];
        part[q * 4 + 0] += xv[j] * w4.x;
        part[q * 4 + 1] += xv[j] * w4.y;
        part[q * 4 + 2] += xv[j] * w4.z;
        part[q * 4 + 3] += xv[j] * w4.w;
      }
    }
    #pragma unroll
    for (int h = 0; h < 16; ++h) red[tid][h] = part[h];
    __syncthreads();
    int h = tid & 15, grp = tid >> 4;
    float s = 0.f;
    #pragma unroll
    for (int k = 0; k < 16; ++k) s += red[grp * 16 + k][h];
    __syncthreads();
    red[grp][h] = s;
    __syncthreads();
    if (tid < 16) {
      float acc = bg[tid];
      #pragma unroll
      for (int k = 0; k < 16; ++k) acc += red[k][tid];
      gsig[(size_t)row * 16 + tid] = 1.0f / (1.0f + __expf(-acc));
    }
  } else if (id < 8192) {
    // ---- weight transpose fp32 [R][C] -> bf16 [C][R] ----
    const float* W; bf16_t* Wt; int R, C, bx, by;
    if (id < 7168) { int local = id - 4096; W = w_qkv; Wt = wqkvT; R = 1024; C = 3072;
                     bx = local % 96; by = local / 96; }
    else           { int local = id - 7168; W = w_out; Wt = woutT; R = 1024; C = 1024;
                     bx = local & 31; by = local >> 5; }
    float (*tile)[33] = (float(*)[33])smem_raw;
    int c0 = bx * 32, r0 = by * 32;
    int tx = tid & 31, ty = tid >> 5;
    #pragma unroll
    for (int i = 0; i < 4; ++i) {
      int r = ty + i * 8;
      tile[r][tx] = W[(size_t)(r0 + r) * C + c0 + tx];
    }
    __syncthreads();
    #pragma unroll
    for (int i = 0; i < 4; ++i) {
      int rr = ty + i * 8;
      Wt[(size_t)(c0 + rr) * R + r0 + tx] = (bf16_t)tile[tx][rr];
    }
  } else {
    // ---- trig table: tc/ts[n][j] = cos/sin(n*freqs[j]) ----
    int idx = (id - 8192) * 256 + tid;   // 65536 total
    int n = idx >> 5, j = idx & 31;
    float f = (float)n * freqs[j];
    tc[idx] = cosf(f);
    ts[idx] = sinf(f);
  }
}

// ---------------- QKV GEMM: dbuf K-loop + fused RoPE + LDS-staged epilogue ----------------
// v3 (measured: 67.9 -> <54us via dbuf single-barrier; FETCH 30MB w/ 2D chunk).
__global__ __launch_bounds__(256) void k_gemm_qkv(const bf16_t* __restrict__ A,
    const bf16_t* __restrict__ Bt, const float* __restrict__ tc,
    const float* __restrict__ ts, bf16_t* __restrict__ Qb,
    bf16_t* __restrict__ Kb, bf16_t* __restrict__ Vb) {
  constexpr int BK = 32, K = 1024;
  constexpr int TP = 136;                         // Tt stride (pad 8 bf16)
  __shared__ __align__(16) char smem[128 * TP * 2];   // 34816 B union
  bf16_t* As0 = (bf16_t*)smem;                    // buf1 = +4096 elems
  bf16_t* Bs0 = (bf16_t*)(smem + 16384);          // buf1 = +4096 elems
  bf16_t* Tt  = (bf16_t*)smem;                    // epilogue staging (aliases all)
  int tid = threadIdx.x, wave = tid >> 6, lane = tid & 63;
  int l16 = lane & 15, quad = lane >> 4;
  // 2D XCD chunk: grid (32,24) -> 8 rectangles of 8x12 blocks, one per XCD.
  int id = blockIdx.y * 32 + blockIdx.x;
  int xcd = id & 7, local = id >> 3;
  int bxi = (xcd & 3) * 8 + (local & 7);
  int byi = (xcd >> 2) * 12 + (local >> 3);
  int bm = bxi * 128, bn = byi * 128;
  int wm = (wave >> 1) * 64, wn = (wave & 1) * 64;
  int srow = wave * 32 + (lane >> 2);
  int scol = (lane & 3) * 8;
  const bf16_t* gA0 = &A [(size_t)(bm + srow)      * K + scol];
  const bf16_t* gA1 = &A [(size_t)(bm + srow + 16) * K + scol];
  const bf16_t* gB0 = &Bt[(size_t)(bn + srow)      * K + scol];
  const bf16_t* gB1 = &Bt[(size_t)(bn + srow + 16) * K + scol];
  bf16_t* lA0 = &As0[(wave * 32)      * BK];      // wave-uniform bases (buf0)
  bf16_t* lA1 = &As0[(wave * 32 + 16) * BK];
  bf16_t* lB0 = &Bs0[(wave * 32)      * BK];
  bf16_t* lB1 = &Bs0[(wave * 32 + 16) * BK];
  f32x4 acc[4][4] = {};
  // prologue: stage tile 0 into buf 0
  GLL16(gA0, lA0); GLL16(gA1, lA1); GLL16(gB0, lB0); GLL16(gB1, lB1);
  __syncthreads();
  for (int k0 = 0; k0 < K; k0 += BK) {
    int cur = (k0 >> 5) & 1;
    int co  = cur * 4096;                 // current buffer elem offset
    int nxt = 4096 - co;                  // next buffer (cur^1) elem offset
    if (k0 + BK < K) {                    // issue next tile BEFORE compute
      GLL16(gA0 + k0 + BK, lA0 + nxt);
      GLL16(gA1 + k0 + BK, lA1 + nxt);
      GLL16(gB0 + k0 + BK, lB0 + nxt);
      GLL16(gB1 + k0 + BK, lB1 + nxt);
    }
    const bf16_t* Asc = As0 + co;
    const bf16_t* Bsc = Bs0 + co;
    bf16x8 af[4], bfr[4];
    #pragma unroll
    for (int t = 0; t < 4; ++t) {
      af[t]  = *(const bf16x8*)&Asc[(wm + t * 16 + l16) * BK + quad * 8];
      bfr[t] = *(const bf16x8*)&Bsc[(wn + t * 16 + l16) * BK + quad * 8];
    }
    #pragma unroll
    for (int mt = 0; mt < 4; ++mt)
      #pragma unroll
      for (int nt = 0; nt < 4; ++nt)
        acc[mt][nt] = __builtin_amdgcn_mfma_f32_16x16x32_bf16(af[mt], bfr[nt], acc[mt][nt], 0, 0, 0);
    __syncthreads();   // single barrier: fences buf[cur] reads + drains buf[cur^1] loads
  }
  // ---- fused epilogue: stage into Tt (aliases As/Bs, safe after final barrier) ----
  if (byi < 16) {
    // Q or K: RoPE on fp32 acc; pairs (2j,2j+1) adjacent lanes -> shfl_xor(1).
    float qs = (byi < 8) ? QSCALE : 1.0f;
    bf16_t* dst = (byi < 8) ? Qb : Kb;
    #pragma unroll
    for (int mt = 0; mt < 4; ++mt)
      #pragma unroll
      for (int r = 0; r < 4; ++r) {
        int row_l = wm + mt * 16 + quad * 4 + r;
        int n = (bm + row_l) & 2047;
        const float* cr = tc + n * 32;
        const float* sr = ts + n * 32;
        #pragma unroll
        for (int nt = 0; nt < 4; ++nt) {
          int col_l = wn + nt * 16 + l16;
          int d = (bn + col_l) & 63, j = d >> 1;
          float val = acc[mt][nt][r];
          float p = __shfl_xor(val, 1);
          float c = cr[j], s = sr[j];
          float o = (d & 1) ? (val * c + p * s) : (val * c - p * s);
          Tt[row_l * TP + col_l] = (bf16_t)(o * qs);
        }
      }
    __syncthreads();
    #pragma unroll
    for (int it = 0; it < 8; ++it) {
      int idx = tid + 256 * it;
      int row_l = idx >> 4, ck = (idx & 15) * 8;
      bf16x8 v = *(const bf16x8*)&Tt[row_l * TP + ck];
      int grow = bm + row_l, b = grow >> 11, n = grow & 2047;
      int col = bn + ck, h = (col >> 6) & 15, d = col & 63;
      *(bf16x8*)&dst[((size_t)(b * H_ + h) * N_ + n) * DH_ + d] = v;
    }
  } else {
    // V: stage transposed (Tt[col][row]) so flush rows are n-contiguous in Vb[bh][d][n].
    #pragma unroll
    for (int mt = 0; mt < 4; ++mt)
      #pragma unroll
      for (int nt = 0; nt < 4; ++nt) {
        int col_l = wn + nt * 16 + l16;
        int row0 = wm + mt * 16 + quad * 4;
        #pragma unroll
        for (int r = 0; r < 4; ++r)
          Tt[col_l * TP + row0 + r] = (bf16_t)acc[mt][nt][r];
      }
    __syncthreads();
    int b = bm >> 11, nb = bm & 2047;
    #pragma unroll
    for (int it = 0; it < 8; ++it) {
      int idx = tid + 256 * it;
      int col_l = idx >> 4, ck = (idx & 15) * 8;
      bf16x8 v = *(const bf16x8*)&Tt[col_l * TP + ck];
      int vcol = bn + col_l - 2048, h = vcol >> 6, d = vcol & 63;
      *(bf16x8*)&Vb[((size_t)(b * H_ + h) * DH_ + d) * N_ + nb + ck] = v;
    }
  }
}

// ---------------- GEMM: 128x64 tile (fp32 out) — out-proj, dbuf K-loop ----------------
// v2: same dbuf single-barrier transform proven on k_gemm_qkv (67.9 -> <54us),
// plus 2D XCD chunk (4x2 rectangles: 3MB unique/XCD vs ~8.3MB 1D). 24KB LDS.
__global__ __launch_bounds__(256) void k_gemm_bt_n64(const bf16_t* __restrict__ A,
    const bf16_t* __restrict__ Bt, float* __restrict__ C, int M, int N, int K) {
  constexpr int BK = 32;
  __shared__ __align__(16) bf16_t As0[128 * BK * 2];   // buf1 = +4096 elems
  __shared__ __align__(16) bf16_t Bs0[64 * BK * 2];    // buf1 = +2048 elems
  int tid = threadIdx.x, wave = tid >> 6, lane = tid & 63;
  int l16 = lane & 15, quad = lane >> 4;
  // 2D XCD chunk: grid (32,16) -> 8 rectangles of 8x8 blocks, one per XCD.
  int id = blockIdx.y * 32 + blockIdx.x;
  int xcd = id & 7, local = id >> 3;
  int bxi = (xcd & 3) * 8 + (local & 7);
  int byi = (xcd >> 2) * 8 + (local >> 3);
  int bm = bxi * 128, bn = byi * 64;
  int wm = (wave >> 1) * 64, wn = (wave & 1) * 32;
  int srow = wave * 32 + (lane >> 2);
  int scol = (lane & 3) * 8;
  const bf16_t* gA0 = &A [(size_t)(bm + srow)      * K + scol];
  const bf16_t* gA1 = &A [(size_t)(bm + srow + 16) * K + scol];
  int srB = wave * 16 + (lane >> 2);
  const bf16_t* gB0 = &Bt[(size_t)(bn + srB) * K + scol];
  bf16_t* lA0 = &As0[(wave * 32)      * BK];
  bf16_t* lA1 = &As0[(wave * 32 + 16) * BK];
  bf16_t* lB0 = &Bs0[(wave * 16)      * BK];
  f32x4 acc[4][2] = {};
  // prologue: stage tile 0 into buf 0
  GLL16(gA0, lA0); GLL16(gA1, lA1); GLL16(gB0, lB0);
  __syncthreads();
  for (int k0 = 0; k0 < K; k0 += BK) {
    int cur = (k0 >> 5) & 1;
    int coA = cur * 4096, nxA = 4096 - coA;
    int coB = cur * 2048, nxB = 2048 - coB;
    if (k0 + BK < K) {                    // issue next tile BEFORE compute
      GLL16(gA0 + k0 + BK, lA0 + nxA);
      GLL16(gA1 + k0 + BK, lA1 + nxA);
      GLL16(gB0 + k0 + BK, lB0 + nxB);
    }
    const bf16_t* Asc = As0 + coA;
    const bf16_t* Bsc = Bs0 + coB;
    bf16x8 af[4], bfr[2];
    #pragma unroll
    for (int t = 0; t < 4; ++t)
      af[t]  = *(const bf16x8*)&Asc[(wm + t * 16 + l16) * BK + quad * 8];
    #pragma unroll
    for (int t = 0; t < 2; ++t)
      bfr[t] = *(const bf16x8*)&Bsc[(wn + t * 16 + l16) * BK + quad * 8];
    #pragma unroll
    for (int mt = 0; mt < 4; ++mt)
      #pragma unroll
      for (int nt = 0; nt < 2; ++nt)
        acc[mt][nt] = __builtin_amdgcn_mfma_f32_16x16x32_bf16(af[mt], bfr[nt], acc[mt][nt], 0, 0, 0);
    __syncthreads();   // single barrier per iter (dbuf)
  }
  #pragma unroll
  for (int mt = 0; mt < 4; ++mt)
    #pragma unroll
    for (int nt = 0; nt < 2; ++nt)
      #pragma unroll
      for (int r = 0; r < 4; ++r) {
        int row = bm + wm + mt * 16 + quad * 4 + r;
        int col = bn + wn + nt * 16 + l16;
        C[(size_t)row * N + col] = acc[mt][nt][r];
      }
}

// ---------------- flash attention: S^T form, fixed-max softmax, 32 q/wave ----------------
// v5 (measured 54.0 µs, MfmaUtil 28%, FETCH 12.8MB): XCD swizzle; softmax 2^x;
// row-sum via ones-MFMA; dbuf K/V + async-STAGE + setprio; single barrier/tile.
__global__ __launch_bounds__(256) void k_flash(const bf16_t* __restrict__ Qb,
    const bf16_t* __restrict__ Kb, const bf16_t* __restrict__ Vb,
    const float* __restrict__ gsig, bf16_t* __restrict__ Ao) {
  __shared__ __align__(16) bf16_t Ks[2][64 * 72];    // [buf][key][dh], stride 72
  __shared__ __align__(16) bf16_t Vt[2][64 * 72];    // [buf][dh][key], stride 72
  __shared__ __align__(16) bf16_t Ps[4][32 * 72];    // per-wave [q][key], stride 72
  int swz = xcd_swizzle_id();                        // grid (16, 32): nwg=512, %8==0
  int qblk = swz & 15, bh = swz >> 4;
  int b = bh >> 4, h = bh & 15;
  int tid = threadIdx.x, wave = tid >> 6, lane = tid & 63;
  int l16 = lane & 15, quad = lane >> 4;
  int qw = qblk * 128 + wave * 32;
  const bf16_t* Qh = Qb + (size_t)bh * N_ * DH_;
  const bf16_t* Kh = Kb + (size_t)bh * N_ * DH_;
  const bf16_t* Vh = Vb + (size_t)bh * DH_ * N_;     // [64][2048]
  bf16_t* Pw = Ps[wave];
  bf16x8 qf[2][2];
  #pragma unroll
  for (int qt = 0; qt < 2; ++qt)
    #pragma unroll
    for (int hf = 0; hf < 2; ++hf)
      qf[qt][hf] = *(const bf16x8*)&Qh[(size_t)(qw + qt * 16 + l16) * DH_ + hf * 32 + quad * 8];
  bf16x8 onesf;
  #pragma unroll
  for (int i = 0; i < 8; ++i) onesf[i] = (bf16_t)1.0f;
  f32x4 accO[2][4] = {};
  f32x4 accL[2] = {};                // row-sum via ones-MFMA; same layout as accO
  int sk = tid >> 3;                 // 0..31
  int sc = (tid & 7) * 8;
  // ---- prologue: stage tile 0 into buf 0 ----
  bf16x8 rk0 = *(const bf16x8*)&Kh[(size_t)sk * DH_ + sc];
  bf16x8 rk1 = *(const bf16x8*)&Kh[(size_t)(sk + 32) * DH_ + sc];
  bf16x8 rv0 = *(const bf16x8*)&Vh[(size_t)sk * N_ + sc];
  bf16x8 rv1 = *(const bf16x8*)&Vh[(size_t)(sk + 32) * N_ + sc];
  *(bf16x8*)&Ks[0][sk * 72 + sc]        = rk0;
  *(bf16x8*)&Ks[0][(sk + 32) * 72 + sc] = rk1;
  *(bf16x8*)&Vt[0][sk * 72 + sc]        = rv0;
  *(bf16x8*)&Vt[0][(sk + 32) * 72 + sc] = rv1;
  __syncthreads();
  const f32x4 zinit = {NEGC, NEGC, NEGC, NEGC};
  for (int k0 = 0; k0 < N_; k0 += 64) {
    int cur = (k0 >> 6) & 1;
    const bf16_t* Kc = Ks[cur];
    const bf16_t* Vc = Vt[cur];
    int kn = k0 + 64;
    if (kn < N_) {
      rk0 = *(const bf16x8*)&Kh[(size_t)(kn + sk) * DH_ + sc];
      rk1 = *(const bf16x8*)&Kh[(size_t)(kn + sk + 32) * DH_ + sc];
      rv0 = *(const bf16x8*)&Vh[(size_t)sk * N_ + kn + sc];
      rv1 = *(const bf16x8*)&Vh[(size_t)(sk + 32) * N_ + kn + sc];
    }
    // S^T = K . Q^T -> C[key][q]; C-init = -8*log2e so st = log2e*(s-8)
    f32x4 st[4][2];
    __builtin_amdgcn_s_setprio(1);
    #pragma unroll
    for (int kt = 0; kt < 4; ++kt) {
      bf16x8 kf0 = *(const bf16x8*)&Kc[(kt * 16 + l16) * 72 + quad * 8];
      bf16x8 kf1 = *(const bf16x8*)&Kc[(kt * 16 + l16) * 72 + 32 + quad * 8];
      #pragma unroll
      for (int qt = 0; qt < 2; ++qt) {
        f32x4 z = zinit;
        z = __builtin_amdgcn_mfma_f32_16x16x32_bf16(kf0, qf[qt][0], z, 0, 0, 0);
        z = __builtin_amdgcn_mfma_f32_16x16x32_bf16(kf1, qf[qt][1], z, 0, 0, 0);
        st[kt][qt] = z;
      }
    }
    __builtin_amdgcn_s_setprio(0);
    // softmax: p = 2^st (bare v_exp_f32)
    #pragma unroll
    for (int qt = 0; qt < 2; ++qt)
      #pragma unroll
      for (int kt = 0; kt < 4; ++kt) {
        bf16x4 pk;
        #pragma unroll
        for (int r = 0; r < 4; ++r)
          pk[r] = (bf16_t)EXP2F(st[kt][qt][r]);
        *(bf16x4*)&Pw[(qt * 16 + l16) * 72 + kt * 16 + quad * 4] = pk;
      }
    // P fragments (A-operand) + PV; row-sum via ones-MFMA on the matrix pipe
    bf16x8 pf[2][2];
    #pragma unroll
    for (int qt = 0; qt < 2; ++qt)
      #pragma unroll
      for (int hf = 0; hf < 2; ++hf)
        pf[qt][hf] = *(const bf16x8*)&Pw[(qt * 16 + l16) * 72 + hf * 32 + quad * 8];
    __builtin_amdgcn_s_setprio(1);
    #pragma unroll
    for (int qt = 0; qt < 2; ++qt) {
      accL[qt] = __builtin_amdgcn_mfma_f32_16x16x32_bf16(pf[qt][0], onesf, accL[qt], 0, 0, 0);
      accL[qt] = __builtin_amdgcn_mfma_f32_16x16x32_bf16(pf[qt][1], onesf, accL[qt], 0, 0, 0);
    }
    #pragma unroll
    for (int dt = 0; dt < 4; ++dt)
      #pragma unroll
      for (int hf = 0; hf < 2; ++hf) {
        bf16x8 vf = *(const bf16x8*)&Vc[(dt * 16 + l16) * 72 + hf * 32 + quad * 8];
        #pragma unroll
        for (int qt = 0; qt < 2; ++qt)
          accO[qt][dt] = __builtin_amdgcn_mfma_f32_16x16x32_bf16(pf[qt][hf], vf, accO[qt][dt], 0, 0, 0);
      }
    __builtin_amdgcn_s_setprio(0);
    if (kn < N_) {
      int nb = cur ^ 1;
      *(bf16x8*)&Ks[nb][sk * 72 + sc]        = rk0;
      *(bf16x8*)&Ks[nb][(sk + 32) * 72 + sc] = rk1;
      *(bf16x8*)&Vt[nb][sk * 72 + sc]        = rv0;
      *(bf16x8*)&Vt[nb][(sk + 32) * 72 + sc] = rv1;
    }
    __syncthreads();
  }
  // epilogue: O and L are both in C layout (q = qt*16+quad*4+r, d = dt*16+l16)
  #pragma unroll
  for (int qt = 0; qt < 2; ++qt)
    #pragma unroll
    for (int r = 0; r < 4; ++r) {
      int q = qw + qt * 16 + quad * 4 + r;
      float g = gsig[((size_t)b * N_ + q) * H_ + h];
      float ginv = g / accL[qt][r];
      #pragma unroll
      for (int dt = 0; dt < 4; ++dt)
        Ao[((size_t)b * N_ + q) * (H_ * DH_) + h * DH_ + dt * 16 + l16] =
            (bf16_t)(accO[qt][dt][r] * ginv);
    }
}

extern "C" void kernel_launch(void* const* d_in, const int* in_sizes, int n_in,
                              void* d_out, int out_size, void* d_ws, size_t ws_size,
                              hipStream_t stream) {
  (void)in_sizes; (void)n_in; (void)out_size; (void)ws_size;
  const float* x      = (const float*)d_in[0];
  const float* gamma  = (const float*)d_in[1];
  const float* w_qkv  = (const float*)d_in[2];
  const float* w_gate = (const float*)d_in[3];
  const float* b_gate = (const float*)d_in[4];
  const float* w_out  = (const float*)d_in[5];
  const float* freqs  = (const float*)d_in[6];
  float* out = (float*)d_out;
  char* ws = (char*)d_ws;
  bf16_t* xn    = (bf16_t*)(ws);                          // 8 MB
  bf16_t* wqkvT = (bf16_t*)(ws + ((size_t)8  << 20));     // 6 MB
  bf16_t* woutT = (bf16_t*)(ws + ((size_t)14 << 20));     // 2 MB
  bf16_t* Qb    = (bf16_t*)(ws + ((size_t)16 << 20));     // 8 MB [bh][n][64]
  bf16_t* Kb    = (bf16_t*)(ws + ((size_t)24 << 20));     // 8 MB [bh][n][64]
  bf16_t* Vb    = (bf16_t*)(ws + ((size_t)32 << 20));     // 8 MB [bh][64][n]
  float*  gsig  = (float*) (ws + ((size_t)40 << 20));     // 256 KB
  bf16_t* attn  = (bf16_t*)(ws + ((size_t)41 << 20));     // 8 MB
  float*  trigc = (float*) (ws + ((size_t)49 << 20));     // 256 KB
  float*  trigs = (float*) (ws + ((size_t)50 << 20));     // 256 KB

  k_prep<<<8448, 256, 0, stream>>>(x, gamma, w_gate, b_gate, xn, gsig,
                                   w_qkv, wqkvT, w_out, woutT, freqs, trigc, trigs);
  k_gemm_qkv<<<dim3(32, 24), 256, 0, stream>>>(xn, wqkvT, trigc, trigs, Qb, Kb, Vb);
  k_flash<<<dim3(16, 32), 256, 0, stream>>>(Qb, Kb, Vb, gsig, attn);
  k_gemm_bt_n64<<<dim3(32, 16), 256, 0, stream>>>(attn, woutT, out, 4096, 1024, 1024);
}